// Round 1
// baseline (389.384 us; speedup 1.0000x reference)
//
#include <hip/hip_runtime.h>
#include <hip/hip_bf16.h>
#include <stdint.h>

// NMS (YOLO-style) for x=(16, 25200, 85) f32 -> out=(16, 300, 6) f32.
// Pipeline: score -> exact top-1024 (radix select on 64-bit keys) ->
// bitonic sort -> pairwise suppression bitmask -> sequential greedy -> output.
// All float math replicates the reference op-for-op (no fast-math, no FMA
// contraction hazards in the decision path).

#define NB 16
#define NA 25200
#define NK 1024
#define ND 300
#define NCLS 80

// monotone transform: larger float <=> larger uint32
__device__ __forceinline__ uint32_t fkey(float f) {
    uint32_t b = __float_as_uint(f);
    return (b & 0x80000000u) ? ~b : (b | 0x80000000u);
}

// ---------------- K1: per-anchor score / class ----------------
// 16 lanes per anchor; 5 strided class reads each (5*16 = 80).
__global__ void score_kernel(const float* __restrict__ x,
                             float* __restrict__ scores,
                             int* __restrict__ clsid) {
    int gid = blockIdx.x * 16 + (threadIdx.x >> 4);
    int lane = threadIdx.x & 15;
    if (gid >= NB * NA) return;
    int b = gid / NA, a = gid % NA;
    const float* p = x + (size_t)(b * NA + a) * 85;
    float obj = p[4];
    float best = -1e30f;
    int bi = 0;
#pragma unroll
    for (int r = 0; r < 5; ++r) {
        int j = lane + 16 * r;
        float v = obj * p[5 + j];
        if (v > best) { best = v; bi = j; }   // strict > keeps first max in-lane
    }
    // reduce across the 16-lane group; tie -> lower class index (jnp.argmax)
    for (int off = 8; off >= 1; off >>= 1) {
        float ov = __shfl_xor(best, off, 16);
        int   oi = __shfl_xor(bi,   off, 16);
        if (ov > best || (ov == best && oi < bi)) { best = ov; bi = oi; }
    }
    if (lane == 0) {
        scores[b * NA + a] = (best > 0.25f) ? best : -1.0f;  // masked score
        clsid[b * NA + a] = bi;
    }
}

// ---------------- K2: exact top-1024 threshold + compact ----------------
// key = (fkey(masked) << 32) | ~idx  -> distinct keys; descending (score desc,
// idx asc) == jax.lax.top_k tie semantics. Radix-select rank 1023, then
// compact all keys >= K* (exactly 1024).
__global__ void select_kernel(const float* __restrict__ scores,
                              unsigned long long* __restrict__ cand) {
    int b = blockIdx.x;
    int t = threadIdx.x;  // 256 threads
    __shared__ unsigned int hist[256];
    __shared__ unsigned long long s_pfx;
    __shared__ unsigned int s_r;
    __shared__ unsigned int s_cnt;
    const float* sc = scores + b * NA;
    if (t == 0) { s_pfx = 0ULL; s_r = NK - 1; }
    __syncthreads();
    for (int pass = 0; pass < 8; ++pass) {
        int bitsdone = pass * 8;
        hist[t] = 0;
        __syncthreads();
        unsigned long long pfx = s_pfx;
        for (int a = t; a < NA; a += 256) {
            unsigned long long k =
                ((unsigned long long)fkey(sc[a]) << 32) | (uint32_t)(~a);
            bool in = (bitsdone == 0) || ((k >> (64 - bitsdone)) == pfx);
            if (in) {
                unsigned int d = (unsigned int)((k >> (56 - bitsdone)) & 0xFF);
                atomicAdd(&hist[d], 1u);
            }
        }
        __syncthreads();
        if (t == 0) {
            unsigned int r = s_r, cum = 0;
            int dsel = 0;
            for (int d = 255; d >= 0; --d) {
                unsigned int c = hist[d];
                if (cum + c > r) { dsel = d; s_r = r - cum; break; }
                cum += c;
            }
            s_pfx = (s_pfx << 8) | (unsigned long long)(unsigned int)dsel;
        }
        __syncthreads();
    }
    unsigned long long Kstar = s_pfx;
    if (t == 0) s_cnt = 0;
    __syncthreads();
    for (int a = t; a < NA; a += 256) {
        unsigned long long k =
            ((unsigned long long)fkey(sc[a]) << 32) | (uint32_t)(~a);
        if (k >= Kstar) {
            unsigned int pos = atomicAdd(&s_cnt, 1u);
            if (pos < NK) cand[b * NK + pos] = k;
        }
    }
}

// ---------------- K3: bitonic sort (descending) + gather ----------------
__global__ void __launch_bounds__(1024)
sort_gather_kernel(const unsigned long long* __restrict__ cand,
                   const float* __restrict__ x,
                   const int* __restrict__ clsid,
                   float4* __restrict__ obox,
                   float* __restrict__ det,
                   unsigned long long* __restrict__ keep0w) {
    int b = blockIdx.x;
    int t = threadIdx.x;  // 1024
    __shared__ unsigned long long sk[NK];
    sk[t] = cand[b * NK + t];
    __syncthreads();
    for (int k = 2; k <= NK; k <<= 1) {
        for (int j = k >> 1; j > 0; j >>= 1) {
            int ixj = t ^ j;
            if (ixj > t) {
                unsigned long long a0 = sk[t], a1 = sk[ixj];
                bool up = ((t & k) == 0);
                bool sw = up ? (a0 < a1) : (a0 > a1);  // descending
                if (sw) { sk[t] = a1; sk[ixj] = a0; }
            }
            __syncthreads();
        }
    }
    unsigned long long key = sk[t];
    int a = (int)(~(uint32_t)key);
    uint32_t u = (uint32_t)(key >> 32);
    uint32_t fb = (u & 0x80000000u) ? (u ^ 0x80000000u) : ~u;
    float s = __uint_as_float(fb);  // masked score (== score when keep0)
    const float* p = x + (size_t)(b * NA + a) * 85;
    float cx = p[0], cy = p[1], w = p[2], h = p[3];
    float x1 = cx - w * 0.5f, y1 = cy - h * 0.5f;
    float x2 = cx + w * 0.5f, y2 = cy + h * 0.5f;
    float c = (float)clsid[b * NA + a];
    float off = c * 7680.0f;  // exact in f32 (integers < 2^24)
    obox[b * NK + t] = make_float4(x1 + off, y1 + off, x2 + off, y2 + off);
    float* dr = det + (size_t)(b * NK + t) * 8;
    dr[0] = x1; dr[1] = y1; dr[2] = x2; dr[3] = y2; dr[4] = s; dr[5] = c;
    bool keep0 = s > 0.25f;
    unsigned long long bal = __ballot(keep0);
    if ((t & 63) == 0) keep0w[b * 16 + (t >> 6)] = bal;
}

// ---------------- K4: suppression bitmask (j > i only) ----------------
__global__ void mask_kernel(const float4* __restrict__ obox,
                            unsigned long long* __restrict__ maskm) {
    int cb = blockIdx.x, rb = blockIdx.y, b = blockIdx.z;
    int t = threadIdx.x;  // 64
    __shared__ float4 cbox[64];
    __shared__ float carea[64];
    int j0 = cb * 64;
    float4 c4 = obox[b * NK + j0 + t];
    cbox[t] = c4;
    carea[t] = (c4.z - c4.x) * (c4.w - c4.y);
    __syncthreads();
    int i = rb * 64 + t;
    float4 r4 = obox[b * NK + i];
    float ra = (r4.z - r4.x) * (r4.w - r4.y);
    unsigned long long word = 0;
    for (int jj = 0; jj < 64; ++jj) {
        int j = j0 + jj;
        if (j > i) {
            float4 o = cbox[jj];
            float ix1 = fmaxf(r4.x, o.x), iy1 = fmaxf(r4.y, o.y);
            float ix2 = fminf(r4.z, o.z), iy2 = fminf(r4.w, o.w);
            float iw = fmaxf(ix2 - ix1, 0.0f), ih = fmaxf(iy2 - iy1, 0.0f);
            float inter = iw * ih;
            float uni = ra + carea[jj] - inter;
            float iou = inter / (uni + 1e-9f);
            if (iou > 0.45f) word |= (1ULL << jj);
        }
    }
    maskm[(size_t)(b * NK + i) * 16 + cb] = word;
}

// ---------------- K5: sequential greedy + output assembly ----------------
__global__ void nms_out_kernel(const unsigned long long* __restrict__ maskm,
                               const unsigned long long* __restrict__ keep0w,
                               const float* __restrict__ det,
                               float* __restrict__ out) {
    int b = blockIdx.x;
    int lane = threadIdx.x;  // 64 (1 wave)
    __shared__ unsigned long long tile[64 * 16];
    __shared__ int list[NK];
    unsigned long long alive = (lane < 16) ? keep0w[b * 16 + lane] : 0ULL;
    for (int tt = 0; tt < 16; ++tt) {
        const unsigned long long* g = maskm + (size_t)(b * NK + tt * 64) * 16;
#pragma unroll
        for (int k = 0; k < 16; ++k) tile[k * 64 + lane] = g[k * 64 + lane];
        __syncthreads();
        for (int r = 0; r < 64; ++r) {
            int i = tt * 64 + r;
            unsigned long long w = __shfl(alive, i >> 6);
            if ((w >> (i & 63)) & 1ULL) {
                if (lane < 16) alive &= ~tile[r * 16 + lane];
            }
        }
        __syncthreads();
    }
    // ordered kept list
    int cnt = (lane < 16) ? __popcll(alive) : 0;
    int pre = cnt;
    for (int off = 1; off < 64; off <<= 1) {
        int v = __shfl_up(pre, off);
        if (lane >= off) pre += v;
    }
    int total = __shfl(pre, 63);
    int base = pre - cnt;
    if (lane < 16) {
        unsigned long long m = alive;
        int pos = base;
        while (m) {
            int bit = __ffsll((long long)m) - 1;
            list[pos++] = lane * 64 + bit;
            m &= m - 1;
        }
    }
    __syncthreads();
    for (int r = lane; r < ND; r += 64) {
        float vals[6] = {0, 0, 0, 0, 0, 0};
        if (r < total) {
            const float* dr = det + (size_t)(b * NK + list[r]) * 8;
#pragma unroll
            for (int c = 0; c < 6; ++c) vals[c] = dr[c];
        }
        float* o = out + (size_t)(b * ND + r) * 6;
#pragma unroll
        for (int c = 0; c < 6; ++c) o[c] = vals[c];
    }
}

extern "C" void kernel_launch(void* const* d_in, const int* in_sizes, int n_in,
                              void* d_out, int out_size, void* d_ws, size_t ws_size,
                              hipStream_t stream) {
    const float* x = (const float*)d_in[0];
    float* out = (float*)d_out;

    char* ws = (char*)d_ws;
    size_t off = 0;
    auto alloc = [&](size_t bytes) {
        void* p = ws + off;
        off += (bytes + 255) & ~(size_t)255;
        return p;
    };
    float* scores = (float*)alloc((size_t)NB * NA * sizeof(float));
    int* clsid = (int*)alloc((size_t)NB * NA * sizeof(int));
    unsigned long long* cand =
        (unsigned long long*)alloc((size_t)NB * NK * sizeof(unsigned long long));
    float4* obox = (float4*)alloc((size_t)NB * NK * sizeof(float4));
    float* det = (float*)alloc((size_t)NB * NK * 8 * sizeof(float));
    unsigned long long* keep0w =
        (unsigned long long*)alloc((size_t)NB * 16 * sizeof(unsigned long long));
    unsigned long long* maskm =
        (unsigned long long*)alloc((size_t)NB * NK * 16 * sizeof(unsigned long long));
    (void)ws_size;

    // K1: 16 anchors per 256-thread block
    score_kernel<<<(NB * NA) / 16, 256, 0, stream>>>(x, scores, clsid);
    // K2: one block per batch
    select_kernel<<<NB, 256, 0, stream>>>(scores, cand);
    // K3: sort + gather
    sort_gather_kernel<<<NB, 1024, 0, stream>>>(cand, x, clsid, obox, det, keep0w);
    // K4: suppression mask
    mask_kernel<<<dim3(16, 16, NB), 64, 0, stream>>>(obox, maskm);
    // K5: greedy NMS + output
    nms_out_kernel<<<NB, 64, 0, stream>>>(maskm, keep0w, det, out);
}

// Round 2
// 256.118 us; speedup vs baseline: 1.5203x; 1.5203x over previous
//
#include <hip/hip_runtime.h>
#include <hip/hip_bf16.h>
#include <stdint.h>

// NMS (YOLO-style) x=(16, 25200, 85) f32 -> out=(16, 300, 6) f32.
// R2: replace 236us single-block radix select with histogram threshold +
// wave-aggregated compact + 2048-wide bitonic sort (exact top-k semantics
// preserved: superset-then-sort-by-full-key == jax.lax.top_k).

#define NB 16
#define NA 25200
#define NK 1024
#define ND 300
#define CAP 2048
#define NBIN 4096

// monotone transform: larger float <=> larger uint32
__device__ __forceinline__ uint32_t fkey(float f) {
    uint32_t b = __float_as_uint(f);
    return (b & 0x80000000u) ? ~b : (b | 0x80000000u);
}

// linear bin over (0.25, 1); identical expression in hist + compact kernels
// on the identical stored float -> identical bin (deterministic IEEE).
__device__ __forceinline__ int score_bin(float s) {
    float f = (s - 0.25f) * (4096.0f / 0.75f);
    int b = (int)f;
    return b > (NBIN - 1) ? (NBIN - 1) : (b < 0 ? 0 : b);
}

// ---------------- K1: per-anchor score / class + histogram ----------------
__global__ void score_kernel(const float* __restrict__ x,
                             float* __restrict__ scores,
                             int* __restrict__ clsid,
                             unsigned int* __restrict__ hist) {
    int gid = blockIdx.x * 16 + (threadIdx.x >> 4);
    int lane = threadIdx.x & 15;
    if (gid >= NB * NA) return;
    int b = gid / NA, a = gid % NA;
    const float* p = x + (size_t)(b * NA + a) * 85;
    float obj = p[4];
    float best = -1e30f;
    int bi = 0;
#pragma unroll
    for (int r = 0; r < 5; ++r) {
        int j = lane + 16 * r;
        float v = obj * p[5 + j];
        if (v > best) { best = v; bi = j; }  // strict > : first max in-lane
    }
    // reduce across 16-lane group; tie -> lower class index (jnp.argmax)
    for (int off = 8; off >= 1; off >>= 1) {
        float ov = __shfl_xor(best, off, 16);
        int   oi = __shfl_xor(bi,   off, 16);
        if (ov > best || (ov == best && oi < bi)) { best = ov; bi = oi; }
    }
    if (lane == 0) {
        bool q = best > 0.25f;
        scores[b * NA + a] = q ? best : -1.0f;
        clsid[b * NA + a] = bi;
        if (q) atomicAdd(&hist[b * NBIN + score_bin(best)], 1u);
    }
}

// ---------------- K2: per-batch threshold bin ----------------
// Find smallest B with count(bins >= B) >= NK (or B=0 if fewer than NK).
__global__ void thresh_kernel(const unsigned int* __restrict__ hist,
                              int* __restrict__ Bsel) {
    int b = blockIdx.x, t = threadIdx.x;  // 256 threads
    __shared__ unsigned int csum[256];
    __shared__ int s_chunk;
    __shared__ unsigned int s_before;
    const unsigned int* h = hist + b * NBIN;
    unsigned int loc[16];
    unsigned int s = 0;
#pragma unroll
    for (int i = 0; i < 16; ++i) { loc[i] = h[t * 16 + i]; s += loc[i]; }
    csum[t] = s;
    __syncthreads();
    if (t == 0) {
        unsigned int cum = 0;
        int sel = -1;
        unsigned int before = 0;
        for (int c = 255; c >= 0; --c) {
            if (cum + csum[c] >= NK) { sel = c; before = cum; break; }
            cum += csum[c];
        }
        if (sel < 0) Bsel[b] = 0;  // fewer than NK candidates total
        s_chunk = sel;
        s_before = before;
    }
    __syncthreads();
    int sel = s_chunk;
    if (sel >= 0 && t == sel) {
        unsigned int cum = s_before;
        int B = 0;
        for (int i = 15; i >= 0; --i) {
            cum += loc[i];
            if (cum >= NK) { B = sel * 16 + i; break; }
        }
        Bsel[b] = B;
    }
}

// ---------------- K3: compact candidates (wave-aggregated atomics) -------
__global__ void compact_kernel(const float* __restrict__ scores,
                               const int* __restrict__ Bsel,
                               unsigned long long* __restrict__ cand,
                               int* __restrict__ cnt) {
    int b = blockIdx.y;
    int a = blockIdx.x * 256 + threadIdx.x;
    if (a >= NA) return;
    float s = scores[b * NA + a];
    int B = Bsel[b];
    bool q = (s > 0.25f) && (score_bin(s) >= B);
    unsigned long long m = __ballot(q);
    if (q) {
        int lane = threadIdx.x & 63;
        int nbelow = __popcll(m & ((1ULL << lane) - 1));
        int leader = __ffsll((long long)m) - 1;
        int base = 0;
        if (lane == leader) base = atomicAdd(&cnt[b], __popcll(m));
        base = __shfl(base, leader);
        int pos = base + nbelow;
        if (pos < CAP)
            cand[b * CAP + pos] =
                ((unsigned long long)fkey(s) << 32) | (uint32_t)(~a);
    }
}

// ---------------- K4: bitonic sort (descending, CAP wide) + gather -------
__global__ void __launch_bounds__(1024)
sort_gather_kernel(const unsigned long long* __restrict__ cand,
                   const int* __restrict__ cnt,
                   const float* __restrict__ x,
                   const int* __restrict__ clsid,
                   float4* __restrict__ obox,
                   float* __restrict__ det,
                   unsigned long long* __restrict__ keep0w) {
    int b = blockIdx.x;
    int t = threadIdx.x;  // 1024
    __shared__ unsigned long long sk[CAP];
    int n = cnt[b];
    if (n > CAP) n = CAP;
    for (int e = t; e < CAP; e += 1024)
        sk[e] = (e < n) ? cand[b * CAP + e] : 0ULL;
    __syncthreads();
    for (int k = 2; k <= CAP; k <<= 1) {
        for (int j = k >> 1; j > 0; j >>= 1) {
            for (int e = t; e < CAP; e += 1024) {
                int ixj = e ^ j;
                if (ixj > e) {
                    unsigned long long a0 = sk[e], a1 = sk[ixj];
                    bool up = ((e & k) == 0);
                    bool sw = up ? (a0 < a1) : (a0 > a1);  // descending
                    if (sw) { sk[e] = a1; sk[ixj] = a0; }
                }
            }
            __syncthreads();
        }
    }
    // keep top NK (threads 0..1023 == elements 0..1023, descending)
    unsigned long long key = sk[t];
    uint32_t u = (uint32_t)(key >> 32);
    int a = (u == 0) ? 0 : (int)(~(uint32_t)key);  // pad-safe index
    uint32_t fb = (u & 0x80000000u) ? (u ^ 0x80000000u) : ~u;
    float s = __uint_as_float(fb);  // masked score (NaN for pad)
    const float* p = x + (size_t)(b * NA + a) * 85;
    float cx = p[0], cy = p[1], w = p[2], h = p[3];
    float x1 = cx - w * 0.5f, y1 = cy - h * 0.5f;
    float x2 = cx + w * 0.5f, y2 = cy + h * 0.5f;
    float c = (float)clsid[b * NA + a];
    float off = c * 7680.0f;
    obox[b * NK + t] = make_float4(x1 + off, y1 + off, x2 + off, y2 + off);
    float* dr = det + (size_t)(b * NK + t) * 8;
    dr[0] = x1; dr[1] = y1; dr[2] = x2; dr[3] = y2; dr[4] = s; dr[5] = c;
    bool keep0 = s > 0.25f;  // false for pad (NaN)
    unsigned long long bal = __ballot(keep0);
    if ((t & 63) == 0) keep0w[b * 16 + (t >> 6)] = bal;
}

// ---------------- K5: suppression bitmask (j > i only) ----------------
__global__ void mask_kernel(const float4* __restrict__ obox,
                            unsigned long long* __restrict__ maskm) {
    int cb = blockIdx.x, rb = blockIdx.y, b = blockIdx.z;
    int t = threadIdx.x;  // 64
    __shared__ float4 cbox[64];
    __shared__ float carea[64];
    int j0 = cb * 64;
    float4 c4 = obox[b * NK + j0 + t];
    cbox[t] = c4;
    carea[t] = (c4.z - c4.x) * (c4.w - c4.y);
    __syncthreads();
    int i = rb * 64 + t;
    float4 r4 = obox[b * NK + i];
    float ra = (r4.z - r4.x) * (r4.w - r4.y);
    unsigned long long word = 0;
    for (int jj = 0; jj < 64; ++jj) {
        int j = j0 + jj;
        if (j > i) {
            float4 o = cbox[jj];
            float ix1 = fmaxf(r4.x, o.x), iy1 = fmaxf(r4.y, o.y);
            float ix2 = fminf(r4.z, o.z), iy2 = fminf(r4.w, o.w);
            float iw = fmaxf(ix2 - ix1, 0.0f), ih = fmaxf(iy2 - iy1, 0.0f);
            float inter = iw * ih;
            float uni = ra + carea[jj] - inter;
            float iou = inter / (uni + 1e-9f);
            if (iou > 0.45f) word |= (1ULL << jj);
        }
    }
    maskm[(size_t)(b * NK + i) * 16 + cb] = word;
}

// ---------------- K6: sequential greedy + output assembly ----------------
__global__ void nms_out_kernel(const unsigned long long* __restrict__ maskm,
                               const unsigned long long* __restrict__ keep0w,
                               const float* __restrict__ det,
                               float* __restrict__ out) {
    int b = blockIdx.x;
    int lane = threadIdx.x;  // 64 (1 wave)
    __shared__ unsigned long long tile[64 * 16];
    __shared__ int list[NK];
    unsigned long long alive = (lane < 16) ? keep0w[b * 16 + lane] : 0ULL;
    for (int tt = 0; tt < 16; ++tt) {
        const unsigned long long* g = maskm + (size_t)(b * NK + tt * 64) * 16;
#pragma unroll
        for (int k = 0; k < 16; ++k) tile[k * 64 + lane] = g[k * 64 + lane];
        __syncthreads();
        for (int r = 0; r < 64; ++r) {
            int i = tt * 64 + r;
            unsigned long long w = __shfl(alive, i >> 6);
            if ((w >> (i & 63)) & 1ULL) {
                if (lane < 16) alive &= ~tile[r * 16 + lane];
            }
        }
        __syncthreads();
    }
    int cnt = (lane < 16) ? __popcll(alive) : 0;
    int pre = cnt;
    for (int off = 1; off < 64; off <<= 1) {
        int v = __shfl_up(pre, off);
        if (lane >= off) pre += v;
    }
    int total = __shfl(pre, 63);
    int base = pre - cnt;
    if (lane < 16) {
        unsigned long long m = alive;
        int pos = base;
        while (m) {
            int bit = __ffsll((long long)m) - 1;
            list[pos++] = lane * 64 + bit;
            m &= m - 1;
        }
    }
    __syncthreads();
    for (int r = lane; r < ND; r += 64) {
        float vals[6] = {0, 0, 0, 0, 0, 0};
        if (r < total) {
            const float* dr = det + (size_t)(b * NK + list[r]) * 8;
#pragma unroll
            for (int c = 0; c < 6; ++c) vals[c] = dr[c];
        }
        float* o = out + (size_t)(b * ND + r) * 6;
#pragma unroll
        for (int c = 0; c < 6; ++c) o[c] = vals[c];
    }
}

extern "C" void kernel_launch(void* const* d_in, const int* in_sizes, int n_in,
                              void* d_out, int out_size, void* d_ws, size_t ws_size,
                              hipStream_t stream) {
    const float* x = (const float*)d_in[0];
    float* out = (float*)d_out;

    char* ws = (char*)d_ws;
    size_t off = 0;
    auto alloc = [&](size_t bytes) {
        void* p = ws + off;
        off += (bytes + 255) & ~(size_t)255;
        return p;
    };
    float* scores = (float*)alloc((size_t)NB * NA * sizeof(float));
    int* clsid = (int*)alloc((size_t)NB * NA * sizeof(int));
    size_t hist_off = off;
    unsigned int* hist =
        (unsigned int*)alloc((size_t)NB * NBIN * sizeof(unsigned int));
    int* cnt = (int*)alloc((size_t)NB * sizeof(int));
    size_t zero_end = off;
    int* Bsel = (int*)alloc((size_t)NB * sizeof(int));
    unsigned long long* cand =
        (unsigned long long*)alloc((size_t)NB * CAP * sizeof(unsigned long long));
    float4* obox = (float4*)alloc((size_t)NB * NK * sizeof(float4));
    float* det = (float*)alloc((size_t)NB * NK * 8 * sizeof(float));
    unsigned long long* keep0w =
        (unsigned long long*)alloc((size_t)NB * 16 * sizeof(unsigned long long));
    unsigned long long* maskm =
        (unsigned long long*)alloc((size_t)NB * NK * 16 * sizeof(unsigned long long));
    (void)ws_size;

    hipMemsetAsync(ws + hist_off, 0, zero_end - hist_off, stream);
    score_kernel<<<(NB * NA) / 16, 256, 0, stream>>>(x, scores, clsid, hist);
    thresh_kernel<<<NB, 256, 0, stream>>>(hist, Bsel);
    compact_kernel<<<dim3((NA + 255) / 256, NB), 256, 0, stream>>>(scores, Bsel,
                                                                   cand, cnt);
    sort_gather_kernel<<<NB, 1024, 0, stream>>>(cand, cnt, x, clsid, obox, det,
                                                keep0w);
    mask_kernel<<<dim3(16, 16, NB), 64, 0, stream>>>(obox, maskm);
    nms_out_kernel<<<NB, 64, 0, stream>>>(maskm, keep0w, det, out);
}

// Round 3
// 170.144 us; speedup vs baseline: 2.2886x; 1.5053x over previous
//
#include <hip/hip_runtime.h>
#include <hip/hip_bf16.h>
#include <stdint.h>

// NMS (YOLO-style) x=(16, 25200, 85) f32 -> out=(16, 300, 6) f32.
// R3: replace the 96us serial greedy scan with Jacobi fixed-point NMS
// (converges to the exact greedy result in chain-depth rounds; ~2-4 here).
// Mask now stores the transpose: supby[i] = bits j<i with iou(i,j)>thr
// (IoU expression is symmetric -> identical float decisions).

#define NB 16
#define NA 25200
#define NK 1024
#define ND 300
#define CAP 2048
#define NBIN 4096

// monotone transform: larger float <=> larger uint32
__device__ __forceinline__ uint32_t fkey(float f) {
    uint32_t b = __float_as_uint(f);
    return (b & 0x80000000u) ? ~b : (b | 0x80000000u);
}

// linear bin over (0.25, 1); identical expression in hist + compact kernels
// on the identical stored float -> identical bin (deterministic IEEE).
__device__ __forceinline__ int score_bin(float s) {
    float f = (s - 0.25f) * (4096.0f / 0.75f);
    int b = (int)f;
    return b > (NBIN - 1) ? (NBIN - 1) : (b < 0 ? 0 : b);
}

// ---------------- K1: per-anchor score / class + histogram ----------------
__global__ void score_kernel(const float* __restrict__ x,
                             float* __restrict__ scores,
                             int* __restrict__ clsid,
                             unsigned int* __restrict__ hist) {
    int gid = blockIdx.x * 16 + (threadIdx.x >> 4);
    int lane = threadIdx.x & 15;
    if (gid >= NB * NA) return;
    int b = gid / NA, a = gid % NA;
    const float* p = x + (size_t)(b * NA + a) * 85;
    float obj = p[4];
    float best = -1e30f;
    int bi = 0;
#pragma unroll
    for (int r = 0; r < 5; ++r) {
        int j = lane + 16 * r;
        float v = obj * p[5 + j];
        if (v > best) { best = v; bi = j; }  // strict > : first max in-lane
    }
    // reduce across 16-lane group; tie -> lower class index (jnp.argmax)
    for (int off = 8; off >= 1; off >>= 1) {
        float ov = __shfl_xor(best, off, 16);
        int   oi = __shfl_xor(bi,   off, 16);
        if (ov > best || (ov == best && oi < bi)) { best = ov; bi = oi; }
    }
    if (lane == 0) {
        bool q = best > 0.25f;
        scores[b * NA + a] = q ? best : -1.0f;
        clsid[b * NA + a] = bi;
        if (q) atomicAdd(&hist[b * NBIN + score_bin(best)], 1u);
    }
}

// ---------------- K2: per-batch threshold bin ----------------
__global__ void thresh_kernel(const unsigned int* __restrict__ hist,
                              int* __restrict__ Bsel) {
    int b = blockIdx.x, t = threadIdx.x;  // 256 threads
    __shared__ unsigned int csum[256];
    __shared__ int s_chunk;
    __shared__ unsigned int s_before;
    const unsigned int* h = hist + b * NBIN;
    unsigned int loc[16];
    unsigned int s = 0;
#pragma unroll
    for (int i = 0; i < 16; ++i) { loc[i] = h[t * 16 + i]; s += loc[i]; }
    csum[t] = s;
    __syncthreads();
    if (t == 0) {
        unsigned int cum = 0;
        int sel = -1;
        unsigned int before = 0;
        for (int c = 255; c >= 0; --c) {
            if (cum + csum[c] >= NK) { sel = c; before = cum; break; }
            cum += csum[c];
        }
        if (sel < 0) Bsel[b] = 0;  // fewer than NK candidates total
        s_chunk = sel;
        s_before = before;
    }
    __syncthreads();
    int sel = s_chunk;
    if (sel >= 0 && t == sel) {
        unsigned int cum = s_before;
        int B = 0;
        for (int i = 15; i >= 0; --i) {
            cum += loc[i];
            if (cum >= NK) { B = sel * 16 + i; break; }
        }
        Bsel[b] = B;
    }
}

// ---------------- K3: compact candidates (wave-aggregated atomics) -------
__global__ void compact_kernel(const float* __restrict__ scores,
                               const int* __restrict__ Bsel,
                               unsigned long long* __restrict__ cand,
                               int* __restrict__ cnt) {
    int b = blockIdx.y;
    int a = blockIdx.x * 256 + threadIdx.x;
    if (a >= NA) return;
    float s = scores[b * NA + a];
    int B = Bsel[b];
    bool q = (s > 0.25f) && (score_bin(s) >= B);
    unsigned long long m = __ballot(q);
    if (q) {
        int lane = threadIdx.x & 63;
        int nbelow = __popcll(m & ((1ULL << lane) - 1));
        int leader = __ffsll((long long)m) - 1;
        int base = 0;
        if (lane == leader) base = atomicAdd(&cnt[b], __popcll(m));
        base = __shfl(base, leader);
        int pos = base + nbelow;
        if (pos < CAP)
            cand[b * CAP + pos] =
                ((unsigned long long)fkey(s) << 32) | (uint32_t)(~a);
    }
}

// ---------------- K4: bitonic sort (descending, CAP wide) + gather -------
__global__ void __launch_bounds__(1024)
sort_gather_kernel(const unsigned long long* __restrict__ cand,
                   const int* __restrict__ cnt,
                   const float* __restrict__ x,
                   const int* __restrict__ clsid,
                   float4* __restrict__ obox,
                   float* __restrict__ det,
                   unsigned long long* __restrict__ keep0w) {
    int b = blockIdx.x;
    int t = threadIdx.x;  // 1024
    __shared__ unsigned long long sk[CAP];
    int n = cnt[b];
    if (n > CAP) n = CAP;
    for (int e = t; e < CAP; e += 1024)
        sk[e] = (e < n) ? cand[b * CAP + e] : 0ULL;
    __syncthreads();
    for (int k = 2; k <= CAP; k <<= 1) {
        for (int j = k >> 1; j > 0; j >>= 1) {
            for (int e = t; e < CAP; e += 1024) {
                int ixj = e ^ j;
                if (ixj > e) {
                    unsigned long long a0 = sk[e], a1 = sk[ixj];
                    bool up = ((e & k) == 0);
                    bool sw = up ? (a0 < a1) : (a0 > a1);  // descending
                    if (sw) { sk[e] = a1; sk[ixj] = a0; }
                }
            }
            __syncthreads();
        }
    }
    // keep top NK (threads 0..1023 == elements 0..1023, descending)
    unsigned long long key = sk[t];
    uint32_t u = (uint32_t)(key >> 32);
    int a = (u == 0) ? 0 : (int)(~(uint32_t)key);  // pad-safe index
    uint32_t fb = (u & 0x80000000u) ? (u ^ 0x80000000u) : ~u;
    float s = __uint_as_float(fb);  // masked score (NaN for pad)
    const float* p = x + (size_t)(b * NA + a) * 85;
    float cx = p[0], cy = p[1], w = p[2], h = p[3];
    float x1 = cx - w * 0.5f, y1 = cy - h * 0.5f;
    float x2 = cx + w * 0.5f, y2 = cy + h * 0.5f;
    float c = (float)clsid[b * NA + a];
    float off = c * 7680.0f;
    obox[b * NK + t] = make_float4(x1 + off, y1 + off, x2 + off, y2 + off);
    float* dr = det + (size_t)(b * NK + t) * 8;
    dr[0] = x1; dr[1] = y1; dr[2] = x2; dr[3] = y2; dr[4] = s; dr[5] = c;
    bool keep0 = s > 0.25f;  // false for pad (NaN)
    unsigned long long bal = __ballot(keep0);
    if ((t & 63) == 0) keep0w[b * 16 + (t >> 6)] = bal;
}

// ---------------- K5: suppressed-by bitmask (j < i), transposed ----------
// maskm[(b*16 + w)*NK + i] = word w of supby(i): bits j in [64w,64w+64), j<i,
// with iou(i,j) > 0.45. Coalesced for the Jacobi row loads.
__global__ void mask_kernel(const float4* __restrict__ obox,
                            unsigned long long* __restrict__ maskm) {
    int cb = blockIdx.x, rb = blockIdx.y, b = blockIdx.z;
    int t = threadIdx.x;  // 64
    int i = rb * 64 + t;
    size_t outidx = (size_t)(b * 16 + cb) * NK + i;
    if (cb > rb) {  // entire word is j > i: zero
        maskm[outidx] = 0ULL;
        return;
    }
    __shared__ float4 cbox[64];
    __shared__ float carea[64];
    int j0 = cb * 64;
    float4 c4 = obox[b * NK + j0 + t];
    cbox[t] = c4;
    carea[t] = (c4.z - c4.x) * (c4.w - c4.y);
    __syncthreads();
    float4 r4 = obox[b * NK + i];
    float ra = (r4.z - r4.x) * (r4.w - r4.y);
    unsigned long long word = 0;
    for (int jj = 0; jj < 64; ++jj) {
        int j = j0 + jj;
        if (j < i) {
            float4 o = cbox[jj];
            float ix1 = fmaxf(r4.x, o.x), iy1 = fmaxf(r4.y, o.y);
            float ix2 = fminf(r4.z, o.z), iy2 = fminf(r4.w, o.w);
            float iw = fmaxf(ix2 - ix1, 0.0f), ih = fmaxf(iy2 - iy1, 0.0f);
            float inter = iw * ih;
            float uni = ra + carea[jj] - inter;
            float iou = inter / (uni + 1e-9f);
            if (iou > 0.45f) word |= (1ULL << jj);
        }
    }
    maskm[outidx] = word;
}

// ---------------- K6: Jacobi fixed-point NMS + output ----------------
// kept(i) = keep0(i) && !exists j<i: kept(j) && sup(j,i). Jacobi iteration
// from alive=keep0 converges to the greedy fixed point in chain-depth rounds.
__global__ void __launch_bounds__(1024)
jacobi_out_kernel(const unsigned long long* __restrict__ maskm,
                  const unsigned long long* __restrict__ keep0w,
                  const float* __restrict__ det,
                  float* __restrict__ out) {
    int b = blockIdx.x;
    int t = threadIdx.x;  // 1024; thread t owns row t
    int wid = t >> 6, lane = t & 63;
    __shared__ unsigned long long aliveS[16];
    __shared__ int changedS;
    __shared__ int list[ND];
    __shared__ int totalS;

    // load my suppressed-by row (16 u64, coalesced across threads)
    unsigned long long row[16];
#pragma unroll
    for (int w = 0; w < 16; ++w)
        row[w] = maskm[(size_t)(b * 16 + w) * NK + t];
    bool keep0 = (keep0w[b * 16 + wid] >> lane) & 1ULL;
    if (t < 16) aliveS[t] = keep0w[b * 16 + t];
    __syncthreads();

    for (int it = 0; it < NK; ++it) {
        if (t == 0) changedS = 0;
        unsigned long long aw[16];
#pragma unroll
        for (int w = 0; w < 16; ++w) aw[w] = aliveS[w];  // snapshot (broadcast)
        __syncthreads();
        unsigned long long sup = 0;
#pragma unroll
        for (int w = 0; w < 16; ++w) sup |= aw[w] & row[w];
        bool newalive = keep0 && (sup == 0);
        unsigned long long bal = __ballot(newalive);
        if (lane == 0) {
            if (bal != aw[wid]) { atomicOr(&changedS, 1); aliveS[wid] = bal; }
        }
        __syncthreads();
        if (!changedS) break;
    }

    // ordered kept list (first ND), single wave
    if (t < 64) {
        unsigned long long av = (lane < 16) ? aliveS[lane] : 0ULL;
        int cnt = (lane < 16) ? __popcll(av) : 0;
        int pre = cnt;
        for (int off = 1; off < 64; off <<= 1) {
            int v = __shfl_up(pre, off);
            if (lane >= off) pre += v;
        }
        int total = __shfl(pre, 63);
        int base = pre - cnt;
        if (lane == 0) totalS = total;
        if (lane < 16) {
            unsigned long long m = av;
            int pos = base;
            while (m && pos < ND) {
                int bit = __ffsll((long long)m) - 1;
                list[pos++] = lane * 64 + bit;
                m &= m - 1;
            }
        }
    }
    __syncthreads();
    if (t < ND) {
        float vals[6] = {0, 0, 0, 0, 0, 0};
        if (t < totalS) {
            const float* dr = det + (size_t)(b * NK + list[t]) * 8;
#pragma unroll
            for (int c = 0; c < 6; ++c) vals[c] = dr[c];
        }
        float* o = out + (size_t)(b * ND + t) * 6;
#pragma unroll
        for (int c = 0; c < 6; ++c) o[c] = vals[c];
    }
}

extern "C" void kernel_launch(void* const* d_in, const int* in_sizes, int n_in,
                              void* d_out, int out_size, void* d_ws, size_t ws_size,
                              hipStream_t stream) {
    const float* x = (const float*)d_in[0];
    float* out = (float*)d_out;

    char* ws = (char*)d_ws;
    size_t off = 0;
    auto alloc = [&](size_t bytes) {
        void* p = ws + off;
        off += (bytes + 255) & ~(size_t)255;
        return p;
    };
    float* scores = (float*)alloc((size_t)NB * NA * sizeof(float));
    int* clsid = (int*)alloc((size_t)NB * NA * sizeof(int));
    size_t hist_off = off;
    unsigned int* hist =
        (unsigned int*)alloc((size_t)NB * NBIN * sizeof(unsigned int));
    int* cnt = (int*)alloc((size_t)NB * sizeof(int));
    size_t zero_end = off;
    int* Bsel = (int*)alloc((size_t)NB * sizeof(int));
    unsigned long long* cand =
        (unsigned long long*)alloc((size_t)NB * CAP * sizeof(unsigned long long));
    float4* obox = (float4*)alloc((size_t)NB * NK * sizeof(float4));
    float* det = (float*)alloc((size_t)NB * NK * 8 * sizeof(float));
    unsigned long long* keep0w =
        (unsigned long long*)alloc((size_t)NB * 16 * sizeof(unsigned long long));
    unsigned long long* maskm =
        (unsigned long long*)alloc((size_t)NB * NK * 16 * sizeof(unsigned long long));
    (void)ws_size;

    hipMemsetAsync(ws + hist_off, 0, zero_end - hist_off, stream);
    score_kernel<<<(NB * NA) / 16, 256, 0, stream>>>(x, scores, clsid, hist);
    thresh_kernel<<<NB, 256, 0, stream>>>(hist, Bsel);
    compact_kernel<<<dim3((NA + 255) / 256, NB), 256, 0, stream>>>(scores, Bsel,
                                                                   cand, cnt);
    sort_gather_kernel<<<NB, 1024, 0, stream>>>(cand, cnt, x, clsid, obox, det,
                                                keep0w);
    mask_kernel<<<dim3(16, 16, NB), 64, 0, stream>>>(obox, maskm);
    jacobi_out_kernel<<<NB, 1024, 0, stream>>>(maskm, keep0w, det, out);
}

// Round 4
// 169.464 us; speedup vs baseline: 2.2977x; 1.0040x over previous
//
#include <hip/hip_runtime.h>
#include <hip/hip_bf16.h>
#include <stdint.h>

// NMS (YOLO-style) x=(16, 25200, 85) f32 -> out=(16, 300, 6) f32.
// R4: replace hipMemsetAsync (rocclr fillBuffer = 77us!) with our own
// parallel zero kernel (~1.5us). Pipeline otherwise unchanged:
// score+hist -> threshold -> compact -> sort+gather -> mask -> jacobi NMS.

#define NB 16
#define NA 25200
#define NK 1024
#define ND 300
#define CAP 2048
#define NBIN 4096

// monotone transform: larger float <=> larger uint32
__device__ __forceinline__ uint32_t fkey(float f) {
    uint32_t b = __float_as_uint(f);
    return (b & 0x80000000u) ? ~b : (b | 0x80000000u);
}

// linear bin over (0.25, 1); identical expression in hist + compact kernels
// on the identical stored float -> identical bin (deterministic IEEE).
__device__ __forceinline__ int score_bin(float s) {
    float f = (s - 0.25f) * (4096.0f / 0.75f);
    int b = (int)f;
    return b > (NBIN - 1) ? (NBIN - 1) : (b < 0 ? 0 : b);
}

// ---------------- K0: zero hist + cnt ----------------
__global__ void zero_kernel(unsigned int* __restrict__ p, int n) {
    int i = blockIdx.x * 256 + threadIdx.x;
    if (i < n) p[i] = 0u;
}

// ---------------- K1: per-anchor score / class + histogram ----------------
__global__ void score_kernel(const float* __restrict__ x,
                             float* __restrict__ scores,
                             int* __restrict__ clsid,
                             unsigned int* __restrict__ hist) {
    int gid = blockIdx.x * 16 + (threadIdx.x >> 4);
    int lane = threadIdx.x & 15;
    if (gid >= NB * NA) return;
    int b = gid / NA, a = gid % NA;
    const float* p = x + (size_t)(b * NA + a) * 85;
    float obj = p[4];
    float best = -1e30f;
    int bi = 0;
#pragma unroll
    for (int r = 0; r < 5; ++r) {
        int j = lane + 16 * r;
        float v = obj * p[5 + j];
        if (v > best) { best = v; bi = j; }  // strict > : first max in-lane
    }
    // reduce across 16-lane group; tie -> lower class index (jnp.argmax)
    for (int off = 8; off >= 1; off >>= 1) {
        float ov = __shfl_xor(best, off, 16);
        int   oi = __shfl_xor(bi,   off, 16);
        if (ov > best || (ov == best && oi < bi)) { best = ov; bi = oi; }
    }
    if (lane == 0) {
        bool q = best > 0.25f;
        scores[b * NA + a] = q ? best : -1.0f;
        clsid[b * NA + a] = bi;
        if (q) atomicAdd(&hist[b * NBIN + score_bin(best)], 1u);
    }
}

// ---------------- K2: per-batch threshold bin ----------------
__global__ void thresh_kernel(const unsigned int* __restrict__ hist,
                              int* __restrict__ Bsel) {
    int b = blockIdx.x, t = threadIdx.x;  // 256 threads
    __shared__ unsigned int csum[256];
    __shared__ int s_chunk;
    __shared__ unsigned int s_before;
    const unsigned int* h = hist + b * NBIN;
    unsigned int loc[16];
    unsigned int s = 0;
#pragma unroll
    for (int i = 0; i < 16; ++i) { loc[i] = h[t * 16 + i]; s += loc[i]; }
    csum[t] = s;
    __syncthreads();
    if (t == 0) {
        unsigned int cum = 0;
        int sel = -1;
        unsigned int before = 0;
        for (int c = 255; c >= 0; --c) {
            if (cum + csum[c] >= NK) { sel = c; before = cum; break; }
            cum += csum[c];
        }
        if (sel < 0) Bsel[b] = 0;  // fewer than NK candidates total
        s_chunk = sel;
        s_before = before;
    }
    __syncthreads();
    int sel = s_chunk;
    if (sel >= 0 && t == sel) {
        unsigned int cum = s_before;
        int B = 0;
        for (int i = 15; i >= 0; --i) {
            cum += loc[i];
            if (cum >= NK) { B = sel * 16 + i; break; }
        }
        Bsel[b] = B;
    }
}

// ---------------- K3: compact candidates (wave-aggregated atomics) -------
__global__ void compact_kernel(const float* __restrict__ scores,
                               const int* __restrict__ Bsel,
                               unsigned long long* __restrict__ cand,
                               int* __restrict__ cnt) {
    int b = blockIdx.y;
    int a = blockIdx.x * 256 + threadIdx.x;
    if (a >= NA) return;
    float s = scores[b * NA + a];
    int B = Bsel[b];
    bool q = (s > 0.25f) && (score_bin(s) >= B);
    unsigned long long m = __ballot(q);
    if (q) {
        int lane = threadIdx.x & 63;
        int nbelow = __popcll(m & ((1ULL << lane) - 1));
        int leader = __ffsll((long long)m) - 1;
        int base = 0;
        if (lane == leader) base = atomicAdd(&cnt[b], __popcll(m));
        base = __shfl(base, leader);
        int pos = base + nbelow;
        if (pos < CAP)
            cand[b * CAP + pos] =
                ((unsigned long long)fkey(s) << 32) | (uint32_t)(~a);
    }
}

// ---------------- K4: bitonic sort (descending, CAP wide) + gather -------
__global__ void __launch_bounds__(1024)
sort_gather_kernel(const unsigned long long* __restrict__ cand,
                   const int* __restrict__ cnt,
                   const float* __restrict__ x,
                   const int* __restrict__ clsid,
                   float4* __restrict__ obox,
                   float* __restrict__ det,
                   unsigned long long* __restrict__ keep0w) {
    int b = blockIdx.x;
    int t = threadIdx.x;  // 1024
    __shared__ unsigned long long sk[CAP];
    int n = cnt[b];
    if (n > CAP) n = CAP;
    for (int e = t; e < CAP; e += 1024)
        sk[e] = (e < n) ? cand[b * CAP + e] : 0ULL;
    __syncthreads();
    for (int k = 2; k <= CAP; k <<= 1) {
        for (int j = k >> 1; j > 0; j >>= 1) {
            for (int e = t; e < CAP; e += 1024) {
                int ixj = e ^ j;
                if (ixj > e) {
                    unsigned long long a0 = sk[e], a1 = sk[ixj];
                    bool up = ((e & k) == 0);
                    bool sw = up ? (a0 < a1) : (a0 > a1);  // descending
                    if (sw) { sk[e] = a1; sk[ixj] = a0; }
                }
            }
            __syncthreads();
        }
    }
    // keep top NK (threads 0..1023 == elements 0..1023, descending)
    unsigned long long key = sk[t];
    uint32_t u = (uint32_t)(key >> 32);
    int a = (u == 0) ? 0 : (int)(~(uint32_t)key);  // pad-safe index
    uint32_t fb = (u & 0x80000000u) ? (u ^ 0x80000000u) : ~u;
    float s = __uint_as_float(fb);  // masked score (NaN for pad)
    const float* p = x + (size_t)(b * NA + a) * 85;
    float cx = p[0], cy = p[1], w = p[2], h = p[3];
    float x1 = cx - w * 0.5f, y1 = cy - h * 0.5f;
    float x2 = cx + w * 0.5f, y2 = cy + h * 0.5f;
    float c = (float)clsid[b * NA + a];
    float off = c * 7680.0f;
    obox[b * NK + t] = make_float4(x1 + off, y1 + off, x2 + off, y2 + off);
    float* dr = det + (size_t)(b * NK + t) * 8;
    dr[0] = x1; dr[1] = y1; dr[2] = x2; dr[3] = y2; dr[4] = s; dr[5] = c;
    bool keep0 = s > 0.25f;  // false for pad (NaN)
    unsigned long long bal = __ballot(keep0);
    if ((t & 63) == 0) keep0w[b * 16 + (t >> 6)] = bal;
}

// ---------------- K5: suppressed-by bitmask (j < i), transposed ----------
// maskm[(b*16 + w)*NK + i] = word w of supby(i): bits j in [64w,64w+64), j<i,
// with iou(i,j) > 0.45. Coalesced for the Jacobi row loads.
__global__ void mask_kernel(const float4* __restrict__ obox,
                            unsigned long long* __restrict__ maskm) {
    int cb = blockIdx.x, rb = blockIdx.y, b = blockIdx.z;
    int t = threadIdx.x;  // 64
    int i = rb * 64 + t;
    size_t outidx = (size_t)(b * 16 + cb) * NK + i;
    if (cb > rb) {  // entire word is j > i: zero
        maskm[outidx] = 0ULL;
        return;
    }
    __shared__ float4 cbox[64];
    __shared__ float carea[64];
    int j0 = cb * 64;
    float4 c4 = obox[b * NK + j0 + t];
    cbox[t] = c4;
    carea[t] = (c4.z - c4.x) * (c4.w - c4.y);
    __syncthreads();
    float4 r4 = obox[b * NK + i];
    float ra = (r4.z - r4.x) * (r4.w - r4.y);
    unsigned long long word = 0;
    for (int jj = 0; jj < 64; ++jj) {
        int j = j0 + jj;
        if (j < i) {
            float4 o = cbox[jj];
            float ix1 = fmaxf(r4.x, o.x), iy1 = fmaxf(r4.y, o.y);
            float ix2 = fminf(r4.z, o.z), iy2 = fminf(r4.w, o.w);
            float iw = fmaxf(ix2 - ix1, 0.0f), ih = fmaxf(iy2 - iy1, 0.0f);
            float inter = iw * ih;
            float uni = ra + carea[jj] - inter;
            float iou = inter / (uni + 1e-9f);
            if (iou > 0.45f) word |= (1ULL << jj);
        }
    }
    maskm[outidx] = word;
}

// ---------------- K6: Jacobi fixed-point NMS + output ----------------
__global__ void __launch_bounds__(1024)
jacobi_out_kernel(const unsigned long long* __restrict__ maskm,
                  const unsigned long long* __restrict__ keep0w,
                  const float* __restrict__ det,
                  float* __restrict__ out) {
    int b = blockIdx.x;
    int t = threadIdx.x;  // 1024; thread t owns row t
    int wid = t >> 6, lane = t & 63;
    __shared__ unsigned long long aliveS[16];
    __shared__ int changedS;
    __shared__ int list[ND];
    __shared__ int totalS;

    // load my suppressed-by row (16 u64, coalesced across threads)
    unsigned long long row[16];
#pragma unroll
    for (int w = 0; w < 16; ++w)
        row[w] = maskm[(size_t)(b * 16 + w) * NK + t];
    bool keep0 = (keep0w[b * 16 + wid] >> lane) & 1ULL;
    if (t < 16) aliveS[t] = keep0w[b * 16 + t];
    __syncthreads();

    for (int it = 0; it < NK; ++it) {
        if (t == 0) changedS = 0;
        unsigned long long aw[16];
#pragma unroll
        for (int w = 0; w < 16; ++w) aw[w] = aliveS[w];  // snapshot (broadcast)
        __syncthreads();
        unsigned long long sup = 0;
#pragma unroll
        for (int w = 0; w < 16; ++w) sup |= aw[w] & row[w];
        bool newalive = keep0 && (sup == 0);
        unsigned long long bal = __ballot(newalive);
        if (lane == 0) {
            if (bal != aw[wid]) { atomicOr(&changedS, 1); aliveS[wid] = bal; }
        }
        __syncthreads();
        if (!changedS) break;
    }

    // ordered kept list (first ND), single wave
    if (t < 64) {
        unsigned long long av = (lane < 16) ? aliveS[lane] : 0ULL;
        int cnt = (lane < 16) ? __popcll(av) : 0;
        int pre = cnt;
        for (int off = 1; off < 64; off <<= 1) {
            int v = __shfl_up(pre, off);
            if (lane >= off) pre += v;
        }
        int total = __shfl(pre, 63);
        int base = pre - cnt;
        if (lane == 0) totalS = total;
        if (lane < 16) {
            unsigned long long m = av;
            int pos = base;
            while (m && pos < ND) {
                int bit = __ffsll((long long)m) - 1;
                list[pos++] = lane * 64 + bit;
                m &= m - 1;
            }
        }
    }
    __syncthreads();
    if (t < ND) {
        float vals[6] = {0, 0, 0, 0, 0, 0};
        if (t < totalS) {
            const float* dr = det + (size_t)(b * NK + list[t]) * 8;
#pragma unroll
            for (int c = 0; c < 6; ++c) vals[c] = dr[c];
        }
        float* o = out + (size_t)(b * ND + t) * 6;
#pragma unroll
        for (int c = 0; c < 6; ++c) o[c] = vals[c];
    }
}

extern "C" void kernel_launch(void* const* d_in, const int* in_sizes, int n_in,
                              void* d_out, int out_size, void* d_ws, size_t ws_size,
                              hipStream_t stream) {
    const float* x = (const float*)d_in[0];
    float* out = (float*)d_out;

    char* ws = (char*)d_ws;
    size_t off = 0;
    auto alloc = [&](size_t bytes) {
        void* p = ws + off;
        off += (bytes + 255) & ~(size_t)255;
        return p;
    };
    float* scores = (float*)alloc((size_t)NB * NA * sizeof(float));
    int* clsid = (int*)alloc((size_t)NB * NA * sizeof(int));
    size_t hist_off = off;
    unsigned int* hist =
        (unsigned int*)alloc((size_t)NB * NBIN * sizeof(unsigned int));
    int* cnt = (int*)alloc((size_t)NB * sizeof(int));
    size_t zero_end = off;
    int* Bsel = (int*)alloc((size_t)NB * sizeof(int));
    unsigned long long* cand =
        (unsigned long long*)alloc((size_t)NB * CAP * sizeof(unsigned long long));
    float4* obox = (float4*)alloc((size_t)NB * NK * sizeof(float4));
    float* det = (float*)alloc((size_t)NB * NK * 8 * sizeof(float));
    unsigned long long* keep0w =
        (unsigned long long*)alloc((size_t)NB * 16 * sizeof(unsigned long long));
    unsigned long long* maskm =
        (unsigned long long*)alloc((size_t)NB * NK * 16 * sizeof(unsigned long long));
    (void)ws_size;

    int zero_n = (int)((zero_end - hist_off) / sizeof(unsigned int));
    zero_kernel<<<(zero_n + 255) / 256, 256, 0, stream>>>(
        (unsigned int*)(ws + hist_off), zero_n);
    score_kernel<<<(NB * NA) / 16, 256, 0, stream>>>(x, scores, clsid, hist);
    thresh_kernel<<<NB, 256, 0, stream>>>(hist, Bsel);
    compact_kernel<<<dim3((NA + 255) / 256, NB), 256, 0, stream>>>(scores, Bsel,
                                                                   cand, cnt);
    sort_gather_kernel<<<NB, 1024, 0, stream>>>(cand, cnt, x, clsid, obox, det,
                                                keep0w);
    mask_kernel<<<dim3(16, 16, NB), 64, 0, stream>>>(obox, maskm);
    jacobi_out_kernel<<<NB, 1024, 0, stream>>>(maskm, keep0w, det, out);
}

// Round 5
// 158.789 us; speedup vs baseline: 2.4522x; 1.0672x over previous
//
#include <hip/hip_runtime.h>
#include <hip/hip_bf16.h>
#include <stdint.h>

// NMS (YOLO-style) x=(16, 25200, 85) f32 -> out=(16, 300, 6) f32.
// R5: register-resident bitonic sort (2 keys/thread in VGPRs; shfl_xor for
// j<=32, register swap for j=1024, LDS only for 64<=j<=512: 30 barriers vs
// 132). Same comparator network -> bit-identical order. Score kernel: 2-D
// grid removes integer div. All decision math unchanged.

#define NB 16
#define NA 25200
#define NK 1024
#define ND 300
#define CAP 2048
#define NBIN 4096

// monotone transform: larger float <=> larger uint32
__device__ __forceinline__ uint32_t fkey(float f) {
    uint32_t b = __float_as_uint(f);
    return (b & 0x80000000u) ? ~b : (b | 0x80000000u);
}

// linear bin over (0.25, 1); identical expression in hist + compact kernels
// on the identical stored float -> identical bin (deterministic IEEE).
__device__ __forceinline__ int score_bin(float s) {
    float f = (s - 0.25f) * (4096.0f / 0.75f);
    int b = (int)f;
    return b > (NBIN - 1) ? (NBIN - 1) : (b < 0 ? 0 : b);
}

// ---------------- K0: zero hist + cnt ----------------
__global__ void zero_kernel(unsigned int* __restrict__ p, int n) {
    int i = blockIdx.x * 256 + threadIdx.x;
    if (i < n) p[i] = 0u;
}

// ---------------- K1: per-anchor score / class + histogram ----------------
__global__ void score_kernel(const float* __restrict__ x,
                             float* __restrict__ scores,
                             int* __restrict__ clsid,
                             unsigned int* __restrict__ hist) {
    int b = blockIdx.y;
    int a = blockIdx.x * 16 + (threadIdx.x >> 4);
    int lane = threadIdx.x & 15;
    const float* p = x + (size_t)(b * NA + a) * 85;
    float obj = p[4];
    float best = -1e30f;
    int bi = 0;
#pragma unroll
    for (int r = 0; r < 5; ++r) {
        int j = lane + 16 * r;
        float v = obj * p[5 + j];
        if (v > best) { best = v; bi = j; }  // strict > : first max in-lane
    }
    // reduce across 16-lane group; tie -> lower class index (jnp.argmax)
    for (int off = 8; off >= 1; off >>= 1) {
        float ov = __shfl_xor(best, off, 16);
        int   oi = __shfl_xor(bi,   off, 16);
        if (ov > best || (ov == best && oi < bi)) { best = ov; bi = oi; }
    }
    if (lane == 0) {
        bool q = best > 0.25f;
        scores[b * NA + a] = q ? best : -1.0f;
        clsid[b * NA + a] = bi;
        if (q) atomicAdd(&hist[b * NBIN + score_bin(best)], 1u);
    }
}

// ---------------- K2: per-batch threshold bin ----------------
__global__ void thresh_kernel(const unsigned int* __restrict__ hist,
                              int* __restrict__ Bsel) {
    int b = blockIdx.x, t = threadIdx.x;  // 256 threads
    __shared__ unsigned int csum[256];
    __shared__ int s_chunk;
    __shared__ unsigned int s_before;
    const unsigned int* h = hist + b * NBIN;
    unsigned int loc[16];
    unsigned int s = 0;
#pragma unroll
    for (int i = 0; i < 16; ++i) { loc[i] = h[t * 16 + i]; s += loc[i]; }
    csum[t] = s;
    __syncthreads();
    if (t == 0) {
        unsigned int cum = 0;
        int sel = -1;
        unsigned int before = 0;
        for (int c = 255; c >= 0; --c) {
            if (cum + csum[c] >= NK) { sel = c; before = cum; break; }
            cum += csum[c];
        }
        if (sel < 0) Bsel[b] = 0;  // fewer than NK candidates total
        s_chunk = sel;
        s_before = before;
    }
    __syncthreads();
    int sel = s_chunk;
    if (sel >= 0 && t == sel) {
        unsigned int cum = s_before;
        int B = 0;
        for (int i = 15; i >= 0; --i) {
            cum += loc[i];
            if (cum >= NK) { B = sel * 16 + i; break; }
        }
        Bsel[b] = B;
    }
}

// ---------------- K3: compact candidates (wave-aggregated atomics) -------
__global__ void compact_kernel(const float* __restrict__ scores,
                               const int* __restrict__ Bsel,
                               unsigned long long* __restrict__ cand,
                               int* __restrict__ cnt) {
    int b = blockIdx.y;
    int a = blockIdx.x * 256 + threadIdx.x;
    if (a >= NA) return;
    float s = scores[b * NA + a];
    int B = Bsel[b];
    bool q = (s > 0.25f) && (score_bin(s) >= B);
    unsigned long long m = __ballot(q);
    if (q) {
        int lane = threadIdx.x & 63;
        int nbelow = __popcll(m & ((1ULL << lane) - 1));
        int leader = __ffsll((long long)m) - 1;
        int base = 0;
        if (lane == leader) base = atomicAdd(&cnt[b], __popcll(m));
        base = __shfl(base, leader);
        int pos = base + nbelow;
        if (pos < CAP)
            cand[b * CAP + pos] =
                ((unsigned long long)fkey(s) << 32) | (uint32_t)(~a);
    }
}

// ---------------- K4: register bitonic sort (desc) + gather -------
// 2 elements/thread (e1=t, e2=t+1024). j<=32: shfl_xor within wave.
// j==1024: both elements are in-thread. 64<=j<=512: LDS exchange.
__global__ void __launch_bounds__(1024)
sort_gather_kernel(const unsigned long long* __restrict__ cand,
                   const int* __restrict__ cnt,
                   const float* __restrict__ x,
                   const int* __restrict__ clsid,
                   float4* __restrict__ obox,
                   float* __restrict__ det,
                   unsigned long long* __restrict__ keep0w) {
    int b = blockIdx.x;
    int t = threadIdx.x;  // 1024
    __shared__ unsigned long long sk[CAP];
    int n = cnt[b];
    if (n > CAP) n = CAP;
    const int e1 = t, e2 = t + 1024;
    unsigned long long v1 = (e1 < n) ? cand[b * CAP + e1] : 0ULL;
    unsigned long long v2 = (e2 < n) ? cand[b * CAP + e2] : 0ULL;

    for (int k = 2; k <= CAP; k <<= 1) {
        for (int j = k >> 1; j > 0; j >>= 1) {
            if (j >= 1024) {
                // partner of e1 is e2 (same thread); k==2048 -> descending
                unsigned long long lo = v1 < v2 ? v1 : v2;
                unsigned long long hi = v1 < v2 ? v2 : v1;
                v1 = hi; v2 = lo;
            } else if (j >= 64) {
                sk[e1] = v1; sk[e2] = v2;
                __syncthreads();
                unsigned long long p1 = sk[e1 ^ j], p2 = sk[e2 ^ j];
                __syncthreads();
                {
                    bool takeMax = (((e1 & j) == 0) == ((e1 & k) == 0));
                    bool g = p1 > v1;
                    v1 = (takeMax == g) ? p1 : v1;
                }
                {
                    bool takeMax = (((e2 & j) == 0) == ((e2 & k) == 0));
                    bool g = p2 > v2;
                    v2 = (takeMax == g) ? p2 : v2;
                }
            } else {
                {
                    unsigned long long p1 =
                        (unsigned long long)__shfl_xor((long long)v1, j);
                    bool takeMax = (((e1 & j) == 0) == ((e1 & k) == 0));
                    bool g = p1 > v1;
                    v1 = (takeMax == g) ? p1 : v1;
                }
                {
                    unsigned long long p2 =
                        (unsigned long long)__shfl_xor((long long)v2, j);
                    bool takeMax = (((e2 & j) == 0) == ((e2 & k) == 0));
                    bool g = p2 > v2;
                    v2 = (takeMax == g) ? p2 : v2;
                }
            }
        }
    }
    // thread t now holds rank-t key in v1 (ranks 0..1023); v2 = 1024..2047
    unsigned long long key = v1;
    uint32_t u = (uint32_t)(key >> 32);
    int a = (u == 0) ? 0 : (int)(~(uint32_t)key);  // pad-safe index
    uint32_t fb = (u & 0x80000000u) ? (u ^ 0x80000000u) : ~u;
    float s = __uint_as_float(fb);  // masked score (NaN for pad)
    const float* p = x + (size_t)(b * NA + a) * 85;
    float cx = p[0], cy = p[1], w = p[2], h = p[3];
    float x1 = cx - w * 0.5f, y1 = cy - h * 0.5f;
    float x2 = cx + w * 0.5f, y2 = cy + h * 0.5f;
    float c = (float)clsid[b * NA + a];
    float off = c * 7680.0f;
    obox[b * NK + t] = make_float4(x1 + off, y1 + off, x2 + off, y2 + off);
    float* dr = det + (size_t)(b * NK + t) * 8;
    dr[0] = x1; dr[1] = y1; dr[2] = x2; dr[3] = y2; dr[4] = s; dr[5] = c;
    bool keep0 = s > 0.25f;  // false for pad (NaN)
    unsigned long long bal = __ballot(keep0);
    if ((t & 63) == 0) keep0w[b * 16 + (t >> 6)] = bal;
}

// ---------------- K5: suppressed-by bitmask (j < i), transposed ----------
__global__ void mask_kernel(const float4* __restrict__ obox,
                            unsigned long long* __restrict__ maskm) {
    int cb = blockIdx.x, rb = blockIdx.y, b = blockIdx.z;
    int t = threadIdx.x;  // 64
    int i = rb * 64 + t;
    size_t outidx = (size_t)(b * 16 + cb) * NK + i;
    if (cb > rb) {  // entire word is j > i: zero
        maskm[outidx] = 0ULL;
        return;
    }
    __shared__ float4 cbox[64];
    __shared__ float carea[64];
    int j0 = cb * 64;
    float4 c4 = obox[b * NK + j0 + t];
    cbox[t] = c4;
    carea[t] = (c4.z - c4.x) * (c4.w - c4.y);
    __syncthreads();
    float4 r4 = obox[b * NK + i];
    float ra = (r4.z - r4.x) * (r4.w - r4.y);
    unsigned long long word = 0;
    for (int jj = 0; jj < 64; ++jj) {
        int j = j0 + jj;
        if (j < i) {
            float4 o = cbox[jj];
            float ix1 = fmaxf(r4.x, o.x), iy1 = fmaxf(r4.y, o.y);
            float ix2 = fminf(r4.z, o.z), iy2 = fminf(r4.w, o.w);
            float iw = fmaxf(ix2 - ix1, 0.0f), ih = fmaxf(iy2 - iy1, 0.0f);
            float inter = iw * ih;
            float uni = ra + carea[jj] - inter;
            float iou = inter / (uni + 1e-9f);
            if (iou > 0.45f) word |= (1ULL << jj);
        }
    }
    maskm[outidx] = word;
}

// ---------------- K6: Jacobi fixed-point NMS + output ----------------
__global__ void __launch_bounds__(1024)
jacobi_out_kernel(const unsigned long long* __restrict__ maskm,
                  const unsigned long long* __restrict__ keep0w,
                  const float* __restrict__ det,
                  float* __restrict__ out) {
    int b = blockIdx.x;
    int t = threadIdx.x;  // 1024; thread t owns row t
    int wid = t >> 6, lane = t & 63;
    __shared__ unsigned long long aliveS[16];
    __shared__ int changedS;
    __shared__ int list[ND];
    __shared__ int totalS;

    unsigned long long row[16];
#pragma unroll
    for (int w = 0; w < 16; ++w)
        row[w] = maskm[(size_t)(b * 16 + w) * NK + t];
    bool keep0 = (keep0w[b * 16 + wid] >> lane) & 1ULL;
    if (t < 16) aliveS[t] = keep0w[b * 16 + t];
    __syncthreads();

    for (int it = 0; it < NK; ++it) {
        if (t == 0) changedS = 0;
        unsigned long long aw[16];
#pragma unroll
        for (int w = 0; w < 16; ++w) aw[w] = aliveS[w];  // snapshot (broadcast)
        __syncthreads();
        unsigned long long sup = 0;
#pragma unroll
        for (int w = 0; w < 16; ++w) sup |= aw[w] & row[w];
        bool newalive = keep0 && (sup == 0);
        unsigned long long bal = __ballot(newalive);
        if (lane == 0) {
            if (bal != aw[wid]) { atomicOr(&changedS, 1); aliveS[wid] = bal; }
        }
        __syncthreads();
        if (!changedS) break;
    }

    if (t < 64) {
        unsigned long long av = (lane < 16) ? aliveS[lane] : 0ULL;
        int cnt = (lane < 16) ? __popcll(av) : 0;
        int pre = cnt;
        for (int off = 1; off < 64; off <<= 1) {
            int v = __shfl_up(pre, off);
            if (lane >= off) pre += v;
        }
        int total = __shfl(pre, 63);
        int base = pre - cnt;
        if (lane == 0) totalS = total;
        if (lane < 16) {
            unsigned long long m = av;
            int pos = base;
            while (m && pos < ND) {
                int bit = __ffsll((long long)m) - 1;
                list[pos++] = lane * 64 + bit;
                m &= m - 1;
            }
        }
    }
    __syncthreads();
    if (t < ND) {
        float vals[6] = {0, 0, 0, 0, 0, 0};
        if (t < totalS) {
            const float* dr = det + (size_t)(b * NK + list[t]) * 8;
#pragma unroll
            for (int c = 0; c < 6; ++c) vals[c] = dr[c];
        }
        float* o = out + (size_t)(b * ND + t) * 6;
#pragma unroll
        for (int c = 0; c < 6; ++c) o[c] = vals[c];
    }
}

extern "C" void kernel_launch(void* const* d_in, const int* in_sizes, int n_in,
                              void* d_out, int out_size, void* d_ws, size_t ws_size,
                              hipStream_t stream) {
    const float* x = (const float*)d_in[0];
    float* out = (float*)d_out;

    char* ws = (char*)d_ws;
    size_t off = 0;
    auto alloc = [&](size_t bytes) {
        void* p = ws + off;
        off += (bytes + 255) & ~(size_t)255;
        return p;
    };
    float* scores = (float*)alloc((size_t)NB * NA * sizeof(float));
    int* clsid = (int*)alloc((size_t)NB * NA * sizeof(int));
    size_t hist_off = off;
    unsigned int* hist =
        (unsigned int*)alloc((size_t)NB * NBIN * sizeof(unsigned int));
    int* cnt = (int*)alloc((size_t)NB * sizeof(int));
    size_t zero_end = off;
    int* Bsel = (int*)alloc((size_t)NB * sizeof(int));
    unsigned long long* cand =
        (unsigned long long*)alloc((size_t)NB * CAP * sizeof(unsigned long long));
    float4* obox = (float4*)alloc((size_t)NB * NK * sizeof(float4));
    float* det = (float*)alloc((size_t)NB * NK * 8 * sizeof(float));
    unsigned long long* keep0w =
        (unsigned long long*)alloc((size_t)NB * 16 * sizeof(unsigned long long));
    unsigned long long* maskm =
        (unsigned long long*)alloc((size_t)NB * NK * 16 * sizeof(unsigned long long));
    (void)ws_size;

    int zero_n = (int)((zero_end - hist_off) / sizeof(unsigned int));
    zero_kernel<<<(zero_n + 255) / 256, 256, 0, stream>>>(
        (unsigned int*)(ws + hist_off), zero_n);
    score_kernel<<<dim3(NA / 16, NB), 256, 0, stream>>>(x, scores, clsid, hist);
    thresh_kernel<<<NB, 256, 0, stream>>>(hist, Bsel);
    compact_kernel<<<dim3((NA + 255) / 256, NB), 256, 0, stream>>>(scores, Bsel,
                                                                   cand, cnt);
    sort_gather_kernel<<<NB, 1024, 0, stream>>>(cand, cnt, x, clsid, obox, det,
                                                keep0w);
    mask_kernel<<<dim3(16, 16, NB), 64, 0, stream>>>(obox, maskm);
    jacobi_out_kernel<<<NB, 1024, 0, stream>>>(maskm, keep0w, det, out);
}

// Round 7
// 97.679 us; speedup vs baseline: 3.9864x; 1.6256x over previous
//
#include <hip/hip_runtime.h>
#include <hip/hip_bf16.h>
#include <stdint.h>

// NMS (YOLO-style) x=(16, 25200, 85) f32 -> out=(16, 300, 6) f32.
// R7 (= R6 + compile fix): fuse thresh+compact+sort into one 16-block kernel
// (parallel suffix scan for the threshold bin, LDS wave-aggregated
// compaction, register bitonic). 5 graph nodes (was 7). Threshold rule,
// candidate set, keys, and IoU math bit-identical to R5.

#define NB 16
#define NA 25200
#define NK 1024
#define ND 300
#define CAP 2048
#define NBIN 4096

// monotone transform: larger float <=> larger uint32
__device__ __forceinline__ uint32_t fkey(float f) {
    uint32_t b = __float_as_uint(f);
    return (b & 0x80000000u) ? ~b : (b | 0x80000000u);
}

// linear bin over (0.25, 1); identical expression where hist is built and
// where it is filtered (same stored float -> identical bin).
__device__ __forceinline__ int score_bin(float s) {
    float f = (s - 0.25f) * (4096.0f / 0.75f);
    int b = (int)f;
    return b > (NBIN - 1) ? (NBIN - 1) : (b < 0 ? 0 : b);
}

// ---------------- K0: zero hist ----------------
__global__ void zero_kernel(unsigned int* __restrict__ p, int n) {
    int i = blockIdx.x * 256 + threadIdx.x;
    if (i < n) p[i] = 0u;
}

// ---------------- K1: per-anchor score / class + histogram ----------------
__global__ void score_kernel(const float* __restrict__ x,
                             float* __restrict__ scores,
                             int* __restrict__ clsid,
                             unsigned int* __restrict__ hist) {
    int b = blockIdx.y;
    int a = blockIdx.x * 16 + (threadIdx.x >> 4);
    int lane = threadIdx.x & 15;
    const float* p = x + (size_t)(b * NA + a) * 85;
    float obj = p[4];
    float best = -1e30f;
    int bi = 0;
#pragma unroll
    for (int r = 0; r < 5; ++r) {
        int j = lane + 16 * r;
        float v = obj * p[5 + j];
        if (v > best) { best = v; bi = j; }  // strict > : first max in-lane
    }
    // reduce across 16-lane group; tie -> lower class index (jnp.argmax)
    for (int off = 8; off >= 1; off >>= 1) {
        float ov = __shfl_xor(best, off, 16);
        int   oi = __shfl_xor(bi,   off, 16);
        if (ov > best || (ov == best && oi < bi)) { best = ov; bi = oi; }
    }
    if (lane == 0) {
        bool q = best > 0.25f;
        scores[b * NA + a] = q ? best : -1.0f;
        clsid[b * NA + a] = bi;
        if (q) atomicAdd(&hist[b * NBIN + score_bin(best)], 1u);
    }
}

// ------- K2: fused threshold + compact + register-bitonic sort + gather ---
// One block per batch, 1024 threads.
// A: suffix-scan hist -> B = max{bin : S(bin) >= NK} (0 if none) -- exact
//    same rule as the serial thresh_kernel.
// B: compact {s>0.25 && bin>=B} into LDS with wave-aggregated LDS atomics.
// C: register bitonic (distinct keys -> same order as any correct sort).
__global__ void __launch_bounds__(1024)
select_sort_kernel(const unsigned int* __restrict__ hist,
                   const float* __restrict__ scores,
                   const float* __restrict__ x,
                   const int* __restrict__ clsid,
                   float4* __restrict__ obox,
                   float* __restrict__ det,
                   unsigned long long* __restrict__ keep0w) {
    int b = blockIdx.x;
    int t = threadIdx.x;  // 1024
    __shared__ unsigned int ssum[1024];
    __shared__ unsigned long long sk[CAP];  // 16 KiB
    __shared__ int sB;
    __shared__ unsigned int scnt;

    // --- phase A: histogram suffix scan ---
    const unsigned int* hrow = hist + b * NBIN;
    uint4 hv = ((const uint4*)hrow)[t];  // bins t*4 .. t*4+3 (256B aligned)
    if (t == 0) { sB = -1; scnt = 0u; }
    sk[t] = 0ULL; sk[t + 1024] = 0ULL;
    ssum[t] = hv.x + hv.y + hv.z + hv.w;
    __syncthreads();
    for (int off = 1; off < 1024; off <<= 1) {
        unsigned int v = ssum[t] + ((t + off < 1024) ? ssum[t + off] : 0u);
        __syncthreads();
        ssum[t] = v;
        __syncthreads();
    }
    // suffix sums of individual bins within my chunk
    unsigned int Snext = (t < 1023) ? ssum[t + 1] : 0u;
    unsigned int s3 = hv.w + Snext;
    unsigned int s2 = hv.z + s3;
    unsigned int s1 = hv.y + s2;
    unsigned int s0 = hv.x + s1;
    int loc = -1;
    if (s3 >= NK) loc = t * 4 + 3;
    else if (s2 >= NK) loc = t * 4 + 2;
    else if (s1 >= NK) loc = t * 4 + 1;
    else if (s0 >= NK) loc = t * 4 + 0;
    for (int off = 32; off >= 1; off >>= 1) {
        int o = __shfl_xor(loc, off);
        loc = o > loc ? o : loc;
    }
    if ((t & 63) == 0) atomicMax(&sB, loc);
    __syncthreads();
    int B = sB < 0 ? 0 : sB;

    // --- phase B: compact candidates into LDS ---
    const float* sc = scores + b * NA;
    for (int a = t; a < NA; a += 1024) {
        float s = sc[a];
        bool q = (s > 0.25f) && (score_bin(s) >= B);
        unsigned long long m = __ballot(q);
        if (q) {
            int lane = t & 63;
            int nbelow = __popcll(m & ((1ULL << lane) - 1));
            int leader = __ffsll((long long)m) - 1;
            unsigned int base = 0;
            if (lane == leader)
                base = atomicAdd(&scnt, (unsigned int)__popcll(m));
            base = __shfl(base, leader);
            unsigned int pos = base + nbelow;
            if (pos < CAP)
                sk[pos] = ((unsigned long long)fkey(s) << 32) | (uint32_t)(~a);
        }
    }
    __syncthreads();

    // --- phase C: register bitonic sort (descending) ---
    const int e1 = t, e2 = t + 1024;
    unsigned long long v1 = sk[e1];
    unsigned long long v2 = sk[e2];
    __syncthreads();
    for (int k = 2; k <= CAP; k <<= 1) {
        for (int j = k >> 1; j > 0; j >>= 1) {
            if (j >= 1024) {
                unsigned long long lo = v1 < v2 ? v1 : v2;
                unsigned long long hi = v1 < v2 ? v2 : v1;
                v1 = hi; v2 = lo;
            } else if (j >= 64) {
                sk[e1] = v1; sk[e2] = v2;
                __syncthreads();
                unsigned long long p1 = sk[e1 ^ j], p2 = sk[e2 ^ j];
                __syncthreads();
                {
                    bool takeMax = (((e1 & j) == 0) == ((e1 & k) == 0));
                    bool g = p1 > v1;
                    v1 = (takeMax == g) ? p1 : v1;
                }
                {
                    bool takeMax = (((e2 & j) == 0) == ((e2 & k) == 0));
                    bool g = p2 > v2;
                    v2 = (takeMax == g) ? p2 : v2;
                }
            } else {
                {
                    unsigned long long p1 =
                        (unsigned long long)__shfl_xor((long long)v1, j);
                    bool takeMax = (((e1 & j) == 0) == ((e1 & k) == 0));
                    bool g = p1 > v1;
                    v1 = (takeMax == g) ? p1 : v1;
                }
                {
                    unsigned long long p2 =
                        (unsigned long long)__shfl_xor((long long)v2, j);
                    bool takeMax = (((e2 & j) == 0) == ((e2 & k) == 0));
                    bool g = p2 > v2;
                    v2 = (takeMax == g) ? p2 : v2;
                }
            }
        }
    }
    // thread t holds rank-t key (ranks 0..1023) in v1
    unsigned long long key = v1;
    uint32_t u = (uint32_t)(key >> 32);
    int a = (u == 0) ? 0 : (int)(~(uint32_t)key);  // pad-safe index
    uint32_t fb = (u & 0x80000000u) ? (u ^ 0x80000000u) : ~u;
    float s = __uint_as_float(fb);  // masked score (NaN for pad)
    const float* p = x + (size_t)(b * NA + a) * 85;
    float cx = p[0], cy = p[1], w = p[2], h = p[3];
    float x1 = cx - w * 0.5f, y1 = cy - h * 0.5f;
    float x2 = cx + w * 0.5f, y2 = cy + h * 0.5f;
    float c = (float)clsid[b * NA + a];
    float off = c * 7680.0f;
    obox[b * NK + t] = make_float4(x1 + off, y1 + off, x2 + off, y2 + off);
    float* dr = det + (size_t)(b * NK + t) * 8;
    dr[0] = x1; dr[1] = y1; dr[2] = x2; dr[3] = y2; dr[4] = s; dr[5] = c;
    bool keep0 = s > 0.25f;  // false for pad (NaN)
    unsigned long long bal = __ballot(keep0);
    if ((t & 63) == 0) keep0w[b * 16 + (t >> 6)] = bal;
}

// ---------------- K3: suppressed-by bitmask (j < i), transposed ----------
// Only lower-triangle word blocks are computed/stored; upper-triangle words
// are implicitly zero (jacobi never reads them).
__global__ void mask_kernel(const float4* __restrict__ obox,
                            unsigned long long* __restrict__ maskm) {
    int cb = blockIdx.x, rb = blockIdx.y, b = blockIdx.z;
    if (cb > rb) return;  // all j > i: implicitly zero, not stored
    int t = threadIdx.x;  // 64
    int i = rb * 64 + t;
    __shared__ float4 cbox[64];
    __shared__ float carea[64];
    int j0 = cb * 64;
    float4 c4 = obox[b * NK + j0 + t];
    cbox[t] = c4;
    carea[t] = (c4.z - c4.x) * (c4.w - c4.y);
    __syncthreads();
    float4 r4 = obox[b * NK + i];
    float ra = (r4.z - r4.x) * (r4.w - r4.y);
    unsigned long long word = 0;
    for (int jj = 0; jj < 64; ++jj) {
        int j = j0 + jj;
        if (j < i) {
            float4 o = cbox[jj];
            float ix1 = fmaxf(r4.x, o.x), iy1 = fmaxf(r4.y, o.y);
            float ix2 = fminf(r4.z, o.z), iy2 = fminf(r4.w, o.w);
            float iw = fmaxf(ix2 - ix1, 0.0f), ih = fmaxf(iy2 - iy1, 0.0f);
            float inter = iw * ih;
            float uni = ra + carea[jj] - inter;
            float iou = inter / (uni + 1e-9f);
            if (iou > 0.45f) word |= (1ULL << jj);
        }
    }
    maskm[(size_t)(b * 16 + cb) * NK + i] = word;
}

// ---------------- K4: Jacobi fixed-point NMS + output ----------------
__global__ void __launch_bounds__(1024)
jacobi_out_kernel(const unsigned long long* __restrict__ maskm,
                  const unsigned long long* __restrict__ keep0w,
                  const float* __restrict__ det,
                  float* __restrict__ out) {
    int b = blockIdx.x;
    int t = threadIdx.x;  // 1024; thread t owns row t
    int wid = t >> 6, lane = t & 63;
    __shared__ unsigned long long aliveS[16];
    __shared__ int changedS;
    __shared__ int list[ND];
    __shared__ int totalS;

    // triangular row load: words w > wid are identically zero
    unsigned long long row[16];
#pragma unroll
    for (int w = 0; w < 16; ++w)
        row[w] = (w <= wid) ? maskm[(size_t)(b * 16 + w) * NK + t] : 0ULL;
    bool keep0 = (keep0w[b * 16 + wid] >> lane) & 1ULL;
    if (t < 16) aliveS[t] = keep0w[b * 16 + t];
    __syncthreads();

    for (int it = 0; it < NK; ++it) {
        if (t == 0) changedS = 0;
        unsigned long long aw[16];
#pragma unroll
        for (int w = 0; w < 16; ++w) aw[w] = aliveS[w];  // snapshot (broadcast)
        __syncthreads();
        unsigned long long sup = 0;
#pragma unroll
        for (int w = 0; w < 16; ++w) sup |= aw[w] & row[w];
        bool newalive = keep0 && (sup == 0);
        unsigned long long bal = __ballot(newalive);
        if (lane == 0) {
            if (bal != aw[wid]) { atomicOr(&changedS, 1); aliveS[wid] = bal; }
        }
        __syncthreads();
        if (!changedS) break;
    }

    if (t < 64) {
        unsigned long long av = (lane < 16) ? aliveS[lane] : 0ULL;
        int cnt = (lane < 16) ? __popcll(av) : 0;
        int pre = cnt;
        for (int off = 1; off < 64; off <<= 1) {
            int v = __shfl_up(pre, off);
            if (lane >= off) pre += v;
        }
        int total = __shfl(pre, 63);
        int base = pre - cnt;
        if (lane == 0) totalS = total;
        if (lane < 16) {
            unsigned long long m = av;
            int pos = base;
            while (m && pos < ND) {
                int bit = __ffsll((long long)m) - 1;
                list[pos++] = lane * 64 + bit;
                m &= m - 1;
            }
        }
    }
    __syncthreads();
    if (t < ND) {
        float vals[6] = {0, 0, 0, 0, 0, 0};
        if (t < totalS) {
            const float* dr = det + (size_t)(b * NK + list[t]) * 8;
#pragma unroll
            for (int c = 0; c < 6; ++c) vals[c] = dr[c];
        }
        float* o = out + (size_t)(b * ND + t) * 6;
#pragma unroll
        for (int c = 0; c < 6; ++c) o[c] = vals[c];
    }
}

extern "C" void kernel_launch(void* const* d_in, const int* in_sizes, int n_in,
                              void* d_out, int out_size, void* d_ws, size_t ws_size,
                              hipStream_t stream) {
    const float* x = (const float*)d_in[0];
    float* out = (float*)d_out;

    char* ws = (char*)d_ws;
    size_t off = 0;
    auto alloc = [&](size_t bytes) {
        void* p = ws + off;
        off += (bytes + 255) & ~(size_t)255;
        return p;
    };
    float* scores = (float*)alloc((size_t)NB * NA * sizeof(float));
    int* clsid = (int*)alloc((size_t)NB * NA * sizeof(int));
    unsigned int* hist =
        (unsigned int*)alloc((size_t)NB * NBIN * sizeof(unsigned int));
    float4* obox = (float4*)alloc((size_t)NB * NK * sizeof(float4));
    float* det = (float*)alloc((size_t)NB * NK * 8 * sizeof(float));
    unsigned long long* keep0w =
        (unsigned long long*)alloc((size_t)NB * 16 * sizeof(unsigned long long));
    unsigned long long* maskm =
        (unsigned long long*)alloc((size_t)NB * NK * 16 * sizeof(unsigned long long));
    (void)ws_size;

    zero_kernel<<<(NB * NBIN + 255) / 256, 256, 0, stream>>>(hist, NB * NBIN);
    score_kernel<<<dim3(NA / 16, NB), 256, 0, stream>>>(x, scores, clsid, hist);
    select_sort_kernel<<<NB, 1024, 0, stream>>>(hist, scores, x, clsid, obox,
                                                det, keep0w);
    mask_kernel<<<dim3(16, 16, NB), 64, 0, stream>>>(obox, maskm);
    jacobi_out_kernel<<<NB, 1024, 0, stream>>>(maskm, keep0w, det, out);
}

// Round 8
// 92.913 us; speedup vs baseline: 4.1908x; 1.0513x over previous
//
#include <hip/hip_runtime.h>
#include <hip/hip_bf16.h>
#include <stdint.h>

// NMS (YOLO-style) x=(16, 25200, 85) f32 -> out=(16, 300, 6) f32.
// R8: histogram built in LDS inside select_sort (from stored scores ->
// bit-identical threshold); zero_kernel + global hist eliminated.
// 4 graph nodes: score -> select_sort -> mask -> jacobi.

#define NB 16
#define NA 25200
#define NK 1024
#define ND 300
#define CAP 2048
#define NBIN 4096

// monotone transform: larger float <=> larger uint32
__device__ __forceinline__ uint32_t fkey(float f) {
    uint32_t b = __float_as_uint(f);
    return (b & 0x80000000u) ? ~b : (b | 0x80000000u);
}

// linear bin over (0.25, 1); applied to the stored score float ->
// deterministic, identical wherever evaluated.
__device__ __forceinline__ int score_bin(float s) {
    float f = (s - 0.25f) * (4096.0f / 0.75f);
    int b = (int)f;
    return b > (NBIN - 1) ? (NBIN - 1) : (b < 0 ? 0 : b);
}

// ---------------- K1: per-anchor score / class ----------------
__global__ void score_kernel(const float* __restrict__ x,
                             float* __restrict__ scores,
                             int* __restrict__ clsid) {
    int b = blockIdx.y;
    int a = blockIdx.x * 16 + (threadIdx.x >> 4);
    int lane = threadIdx.x & 15;
    const float* p = x + (size_t)(b * NA + a) * 85;
    float obj = p[4];
    float best = -1e30f;
    int bi = 0;
#pragma unroll
    for (int r = 0; r < 5; ++r) {
        int j = lane + 16 * r;
        float v = obj * p[5 + j];
        if (v > best) { best = v; bi = j; }  // strict > : first max in-lane
    }
    // reduce across 16-lane group; tie -> lower class index (jnp.argmax)
    for (int off = 8; off >= 1; off >>= 1) {
        float ov = __shfl_xor(best, off, 16);
        int   oi = __shfl_xor(bi,   off, 16);
        if (ov > best || (ov == best && oi < bi)) { best = ov; bi = oi; }
    }
    if (lane == 0) {
        bool q = best > 0.25f;
        scores[b * NA + a] = q ? best : -1.0f;
        clsid[b * NA + a] = bi;
    }
}

// -- K2: LDS hist + threshold + compact + register-bitonic sort + gather --
// One block per batch, 1024 threads.
// A0: build 4096-bin histogram of qualifying scores in LDS.
// A:  suffix-scan -> B = max{bin : S(bin) >= NK} (0 if none).
// B:  compact {s>0.25 && bin>=B} into LDS with wave-aggregated atomics.
// C:  register bitonic (distinct keys -> exact top_k order).
__global__ void __launch_bounds__(1024)
select_sort_kernel(const float* __restrict__ scores,
                   const float* __restrict__ x,
                   const int* __restrict__ clsid,
                   float4* __restrict__ obox,
                   float* __restrict__ det,
                   unsigned long long* __restrict__ keep0w) {
    int b = blockIdx.x;
    int t = threadIdx.x;  // 1024
    __shared__ unsigned int lhist[NBIN];  // 16 KiB
    __shared__ unsigned int ssum[1024];   // 4 KiB
    __shared__ unsigned long long sk[CAP];  // 16 KiB
    __shared__ int sB;
    __shared__ unsigned int scnt;

    // --- phase A0: zero + build LDS histogram ---
    ((uint4*)lhist)[t] = make_uint4(0u, 0u, 0u, 0u);
    sk[t] = 0ULL; sk[t + 1024] = 0ULL;
    if (t == 0) { sB = -1; scnt = 0u; }
    __syncthreads();
    const float* sc = scores + b * NA;
    for (int a = t; a < NA; a += 1024) {
        float s = sc[a];
        if (s > 0.25f) atomicAdd(&lhist[score_bin(s)], 1u);
    }
    __syncthreads();

    // --- phase A: histogram suffix scan ---
    uint4 hv = ((const uint4*)lhist)[t];  // bins t*4 .. t*4+3
    ssum[t] = hv.x + hv.y + hv.z + hv.w;
    __syncthreads();
    for (int off = 1; off < 1024; off <<= 1) {
        unsigned int v = ssum[t] + ((t + off < 1024) ? ssum[t + off] : 0u);
        __syncthreads();
        ssum[t] = v;
        __syncthreads();
    }
    // suffix sums of individual bins within my chunk
    unsigned int Snext = (t < 1023) ? ssum[t + 1] : 0u;
    unsigned int s3 = hv.w + Snext;
    unsigned int s2 = hv.z + s3;
    unsigned int s1 = hv.y + s2;
    unsigned int s0 = hv.x + s1;
    int loc = -1;
    if (s3 >= NK) loc = t * 4 + 3;
    else if (s2 >= NK) loc = t * 4 + 2;
    else if (s1 >= NK) loc = t * 4 + 1;
    else if (s0 >= NK) loc = t * 4 + 0;
    for (int off = 32; off >= 1; off >>= 1) {
        int o = __shfl_xor(loc, off);
        loc = o > loc ? o : loc;
    }
    if ((t & 63) == 0) atomicMax(&sB, loc);
    __syncthreads();
    int B = sB < 0 ? 0 : sB;

    // --- phase B: compact candidates into LDS ---
    for (int a = t; a < NA; a += 1024) {
        float s = sc[a];
        bool q = (s > 0.25f) && (score_bin(s) >= B);
        unsigned long long m = __ballot(q);
        if (q) {
            int lane = t & 63;
            int nbelow = __popcll(m & ((1ULL << lane) - 1));
            int leader = __ffsll((long long)m) - 1;
            unsigned int base = 0;
            if (lane == leader)
                base = atomicAdd(&scnt, (unsigned int)__popcll(m));
            base = __shfl(base, leader);
            unsigned int pos = base + nbelow;
            if (pos < CAP)
                sk[pos] = ((unsigned long long)fkey(s) << 32) | (uint32_t)(~a);
        }
    }
    __syncthreads();

    // --- phase C: register bitonic sort (descending) ---
    const int e1 = t, e2 = t + 1024;
    unsigned long long v1 = sk[e1];
    unsigned long long v2 = sk[e2];
    __syncthreads();
    for (int k = 2; k <= CAP; k <<= 1) {
        for (int j = k >> 1; j > 0; j >>= 1) {
            if (j >= 1024) {
                unsigned long long lo = v1 < v2 ? v1 : v2;
                unsigned long long hi = v1 < v2 ? v2 : v1;
                v1 = hi; v2 = lo;
            } else if (j >= 64) {
                sk[e1] = v1; sk[e2] = v2;
                __syncthreads();
                unsigned long long p1 = sk[e1 ^ j], p2 = sk[e2 ^ j];
                __syncthreads();
                {
                    bool takeMax = (((e1 & j) == 0) == ((e1 & k) == 0));
                    bool g = p1 > v1;
                    v1 = (takeMax == g) ? p1 : v1;
                }
                {
                    bool takeMax = (((e2 & j) == 0) == ((e2 & k) == 0));
                    bool g = p2 > v2;
                    v2 = (takeMax == g) ? p2 : v2;
                }
            } else {
                {
                    unsigned long long p1 =
                        (unsigned long long)__shfl_xor((long long)v1, j);
                    bool takeMax = (((e1 & j) == 0) == ((e1 & k) == 0));
                    bool g = p1 > v1;
                    v1 = (takeMax == g) ? p1 : v1;
                }
                {
                    unsigned long long p2 =
                        (unsigned long long)__shfl_xor((long long)v2, j);
                    bool takeMax = (((e2 & j) == 0) == ((e2 & k) == 0));
                    bool g = p2 > v2;
                    v2 = (takeMax == g) ? p2 : v2;
                }
            }
        }
    }
    // thread t holds rank-t key (ranks 0..1023) in v1
    unsigned long long key = v1;
    uint32_t u = (uint32_t)(key >> 32);
    int a = (u == 0) ? 0 : (int)(~(uint32_t)key);  // pad-safe index
    uint32_t fb = (u & 0x80000000u) ? (u ^ 0x80000000u) : ~u;
    float s = __uint_as_float(fb);  // masked score (NaN for pad)
    const float* p = x + (size_t)(b * NA + a) * 85;
    float cx = p[0], cy = p[1], w = p[2], h = p[3];
    float x1 = cx - w * 0.5f, y1 = cy - h * 0.5f;
    float x2 = cx + w * 0.5f, y2 = cy + h * 0.5f;
    float c = (float)clsid[b * NA + a];
    float off = c * 7680.0f;
    obox[b * NK + t] = make_float4(x1 + off, y1 + off, x2 + off, y2 + off);
    float* dr = det + (size_t)(b * NK + t) * 8;
    dr[0] = x1; dr[1] = y1; dr[2] = x2; dr[3] = y2; dr[4] = s; dr[5] = c;
    bool keep0 = s > 0.25f;  // false for pad (NaN)
    unsigned long long bal = __ballot(keep0);
    if ((t & 63) == 0) keep0w[b * 16 + (t >> 6)] = bal;
}

// ---------------- K3: suppressed-by bitmask (j < i), transposed ----------
// Only lower-triangle word blocks are computed/stored; upper-triangle words
// are implicitly zero (jacobi never reads them).
__global__ void mask_kernel(const float4* __restrict__ obox,
                            unsigned long long* __restrict__ maskm) {
    int cb = blockIdx.x, rb = blockIdx.y, b = blockIdx.z;
    if (cb > rb) return;  // all j > i: implicitly zero, not stored
    int t = threadIdx.x;  // 64
    int i = rb * 64 + t;
    __shared__ float4 cbox[64];
    __shared__ float carea[64];
    int j0 = cb * 64;
    float4 c4 = obox[b * NK + j0 + t];
    cbox[t] = c4;
    carea[t] = (c4.z - c4.x) * (c4.w - c4.y);
    __syncthreads();
    float4 r4 = obox[b * NK + i];
    float ra = (r4.z - r4.x) * (r4.w - r4.y);
    unsigned long long word = 0;
    for (int jj = 0; jj < 64; ++jj) {
        int j = j0 + jj;
        if (j < i) {
            float4 o = cbox[jj];
            float ix1 = fmaxf(r4.x, o.x), iy1 = fmaxf(r4.y, o.y);
            float ix2 = fminf(r4.z, o.z), iy2 = fminf(r4.w, o.w);
            float iw = fmaxf(ix2 - ix1, 0.0f), ih = fmaxf(iy2 - iy1, 0.0f);
            float inter = iw * ih;
            float uni = ra + carea[jj] - inter;
            float iou = inter / (uni + 1e-9f);
            if (iou > 0.45f) word |= (1ULL << jj);
        }
    }
    maskm[(size_t)(b * 16 + cb) * NK + i] = word;
}

// ---------------- K4: Jacobi fixed-point NMS + output ----------------
__global__ void __launch_bounds__(1024)
jacobi_out_kernel(const unsigned long long* __restrict__ maskm,
                  const unsigned long long* __restrict__ keep0w,
                  const float* __restrict__ det,
                  float* __restrict__ out) {
    int b = blockIdx.x;
    int t = threadIdx.x;  // 1024; thread t owns row t
    int wid = t >> 6, lane = t & 63;
    __shared__ unsigned long long aliveS[16];
    __shared__ int changedS;
    __shared__ int list[ND];
    __shared__ int totalS;

    // triangular row load: words w > wid are identically zero
    unsigned long long row[16];
#pragma unroll
    for (int w = 0; w < 16; ++w)
        row[w] = (w <= wid) ? maskm[(size_t)(b * 16 + w) * NK + t] : 0ULL;
    bool keep0 = (keep0w[b * 16 + wid] >> lane) & 1ULL;
    if (t < 16) aliveS[t] = keep0w[b * 16 + t];
    __syncthreads();

    for (int it = 0; it < NK; ++it) {
        if (t == 0) changedS = 0;
        unsigned long long aw[16];
#pragma unroll
        for (int w = 0; w < 16; ++w) aw[w] = aliveS[w];  // snapshot (broadcast)
        __syncthreads();
        unsigned long long sup = 0;
#pragma unroll
        for (int w = 0; w < 16; ++w) sup |= aw[w] & row[w];
        bool newalive = keep0 && (sup == 0);
        unsigned long long bal = __ballot(newalive);
        if (lane == 0) {
            if (bal != aw[wid]) { atomicOr(&changedS, 1); aliveS[wid] = bal; }
        }
        __syncthreads();
        if (!changedS) break;
    }

    if (t < 64) {
        unsigned long long av = (lane < 16) ? aliveS[lane] : 0ULL;
        int cnt = (lane < 16) ? __popcll(av) : 0;
        int pre = cnt;
        for (int off = 1; off < 64; off <<= 1) {
            int v = __shfl_up(pre, off);
            if (lane >= off) pre += v;
        }
        int total = __shfl(pre, 63);
        int base = pre - cnt;
        if (lane == 0) totalS = total;
        if (lane < 16) {
            unsigned long long m = av;
            int pos = base;
            while (m && pos < ND) {
                int bit = __ffsll((long long)m) - 1;
                list[pos++] = lane * 64 + bit;
                m &= m - 1;
            }
        }
    }
    __syncthreads();
    if (t < ND) {
        float vals[6] = {0, 0, 0, 0, 0, 0};
        if (t < totalS) {
            const float* dr = det + (size_t)(b * NK + list[t]) * 8;
#pragma unroll
            for (int c = 0; c < 6; ++c) vals[c] = dr[c];
        }
        float* o = out + (size_t)(b * ND + t) * 6;
#pragma unroll
        for (int c = 0; c < 6; ++c) o[c] = vals[c];
    }
}

extern "C" void kernel_launch(void* const* d_in, const int* in_sizes, int n_in,
                              void* d_out, int out_size, void* d_ws, size_t ws_size,
                              hipStream_t stream) {
    const float* x = (const float*)d_in[0];
    float* out = (float*)d_out;

    char* ws = (char*)d_ws;
    size_t off = 0;
    auto alloc = [&](size_t bytes) {
        void* p = ws + off;
        off += (bytes + 255) & ~(size_t)255;
        return p;
    };
    float* scores = (float*)alloc((size_t)NB * NA * sizeof(float));
    int* clsid = (int*)alloc((size_t)NB * NA * sizeof(int));
    float4* obox = (float4*)alloc((size_t)NB * NK * sizeof(float4));
    float* det = (float*)alloc((size_t)NB * NK * 8 * sizeof(float));
    unsigned long long* keep0w =
        (unsigned long long*)alloc((size_t)NB * 16 * sizeof(unsigned long long));
    unsigned long long* maskm =
        (unsigned long long*)alloc((size_t)NB * NK * 16 * sizeof(unsigned long long));
    (void)ws_size;

    score_kernel<<<dim3(NA / 16, NB), 256, 0, stream>>>(x, scores, clsid);
    select_sort_kernel<<<NB, 1024, 0, stream>>>(scores, x, clsid, obox, det,
                                                keep0w);
    mask_kernel<<<dim3(16, 16, NB), 64, 0, stream>>>(obox, maskm);
    jacobi_out_kernel<<<NB, 1024, 0, stream>>>(maskm, keep0w, det, out);
}

// Round 9
// 83.893 us; speedup vs baseline: 4.6414x; 1.1075x over previous
//
#include <hip/hip_runtime.h>
#include <hip/hip_bf16.h>
#include <stdint.h>

// NMS (YOLO-style) x=(16, 25200, 85) f32 -> out=(16, 300, 6) f32.
// R9: (1) xyxy boxes precomputed in score_kernel (ss gather becomes one
// L2-resident 16B load), (2) select_sort: float4 streaming + wave-shfl
// suffix scan (2 barriers instead of 20), (3) mask: exact class prefilter
// (different classes are >=7678 apart -> IoU exactly 0). All decision
// floats bit-identical to R8.

#define NB 16
#define NA 25200
#define NK 1024
#define ND 300
#define CAP 2048
#define NBIN 4096

// monotone transform: larger float <=> larger uint32
__device__ __forceinline__ uint32_t fkey(float f) {
    uint32_t b = __float_as_uint(f);
    return (b & 0x80000000u) ? ~b : (b | 0x80000000u);
}

// linear bin over (0.25, 1); applied to the stored score float ->
// deterministic, identical wherever evaluated.
__device__ __forceinline__ int score_bin(float s) {
    float f = (s - 0.25f) * (4096.0f / 0.75f);
    int b = (int)f;
    return b > (NBIN - 1) ? (NBIN - 1) : (b < 0 ? 0 : b);
}

// ---------------- K1: per-anchor score / class / xyxy box ----------------
__global__ void score_kernel(const float* __restrict__ x,
                             float* __restrict__ scores,
                             int* __restrict__ clsid,
                             float4* __restrict__ boxes) {
    int b = blockIdx.y;
    int a = blockIdx.x * 16 + (threadIdx.x >> 4);
    int lane = threadIdx.x & 15;
    const float* p = x + (size_t)(b * NA + a) * 85;
    float obj = p[4];
    float best = -1e30f;
    int bi = 0;
#pragma unroll
    for (int r = 0; r < 5; ++r) {
        int j = lane + 16 * r;
        float v = obj * p[5 + j];
        if (v > best) { best = v; bi = j; }  // strict > : first max in-lane
    }
    // reduce across 16-lane group; tie -> lower class index (jnp.argmax)
    for (int off = 8; off >= 1; off >>= 1) {
        float ov = __shfl_xor(best, off, 16);
        int   oi = __shfl_xor(bi,   off, 16);
        if (ov > best || (ov == best && oi < bi)) { best = ov; bi = oi; }
    }
    if (lane == 0) {
        bool q = best > 0.25f;
        scores[b * NA + a] = q ? best : -1.0f;
        clsid[b * NA + a] = bi;
        float cx = p[0], cy = p[1], w = p[2], h = p[3];
        boxes[b * NA + a] = make_float4(cx - w * 0.5f, cy - h * 0.5f,
                                        cx + w * 0.5f, cy + h * 0.5f);
    }
}

// -- K2: LDS hist + threshold + compact + register-bitonic sort + gather --
// One block per batch, 1024 threads.
__global__ void __launch_bounds__(1024)
select_sort_kernel(const float* __restrict__ scores,
                   const float4* __restrict__ boxes,
                   const int* __restrict__ clsid,
                   float4* __restrict__ obox,
                   float* __restrict__ det,
                   unsigned long long* __restrict__ keep0w) {
    int b = blockIdx.x;
    int t = threadIdx.x;  // 1024
    int wid = t >> 6, lane = t & 63;
    __shared__ unsigned int lhist[NBIN];     // 16 KiB
    __shared__ unsigned long long sk[CAP];   // 16 KiB
    __shared__ unsigned int wsum[16];
    __shared__ int sB;
    __shared__ unsigned int scnt;

    // --- phase A0: zero + build LDS histogram (float4 stream) ---
    ((uint4*)lhist)[t] = make_uint4(0u, 0u, 0u, 0u);
    sk[t] = 0ULL; sk[t + 1024] = 0ULL;
    if (t == 0) { sB = -1; scnt = 0u; }
    __syncthreads();
    const float* sc = scores + b * NA;
    const float4* sc4 = (const float4*)sc;  // NA % 4 == 0, 16B-aligned
    for (int i = t; i < NA / 4; i += 1024) {
        float4 s4 = sc4[i];
        if (s4.x > 0.25f) atomicAdd(&lhist[score_bin(s4.x)], 1u);
        if (s4.y > 0.25f) atomicAdd(&lhist[score_bin(s4.y)], 1u);
        if (s4.z > 0.25f) atomicAdd(&lhist[score_bin(s4.z)], 1u);
        if (s4.w > 0.25f) atomicAdd(&lhist[score_bin(s4.w)], 1u);
    }
    __syncthreads();

    // --- phase A: suffix scan via wave shfl (S_t = sum of bins >= t*4) ---
    uint4 hv = ((const uint4*)lhist)[t];  // bins t*4 .. t*4+3
    unsigned int mysum = hv.x + hv.y + hv.z + hv.w;
    unsigned int ssfx = mysum;  // suffix over chunk-sums within my wave
#pragma unroll
    for (int off = 1; off < 64; off <<= 1) {
        unsigned int v = __shfl_down(ssfx, off);
        if (lane + off < 64) ssfx += v;
    }
    if (lane == 0) wsum[wid] = ssfx;  // wave totals
    __syncthreads();
    unsigned int tail = 0;
    for (int w2 = wid + 1; w2 < 16; ++w2) tail += wsum[w2];
    unsigned int S_t = ssfx + tail;        // suffix from my chunk start
    unsigned int Snext = S_t - mysum;      // suffix from next chunk
    unsigned int s3 = hv.w + Snext;
    unsigned int s2 = hv.z + s3;
    unsigned int s1 = hv.y + s2;
    unsigned int s0 = hv.x + s1;
    int loc = -1;
    if (s3 >= NK) loc = t * 4 + 3;
    else if (s2 >= NK) loc = t * 4 + 2;
    else if (s1 >= NK) loc = t * 4 + 1;
    else if (s0 >= NK) loc = t * 4 + 0;
#pragma unroll
    for (int off = 32; off >= 1; off >>= 1) {
        int o = __shfl_xor(loc, off);
        loc = o > loc ? o : loc;
    }
    if ((t & 63) == 0) atomicMax(&sB, loc);
    __syncthreads();
    int B = sB < 0 ? 0 : sB;

    // --- phase B: compact candidates into LDS (float4 stream) ---
    for (int i = t; i < NA / 4; i += 1024) {
        float4 s4 = sc4[i];
        float se[4] = {s4.x, s4.y, s4.z, s4.w};
#pragma unroll
        for (int e = 0; e < 4; ++e) {
            float s = se[e];
            int a = i * 4 + e;
            bool q = (s > 0.25f) && (score_bin(s) >= B);
            unsigned long long m = __ballot(q);
            if (q) {
                int nbelow = __popcll(m & ((1ULL << lane) - 1));
                int leader = __ffsll((long long)m) - 1;
                unsigned int base = 0;
                if (lane == leader)
                    base = atomicAdd(&scnt, (unsigned int)__popcll(m));
                base = __shfl(base, leader);
                unsigned int pos = base + nbelow;
                if (pos < CAP)
                    sk[pos] =
                        ((unsigned long long)fkey(s) << 32) | (uint32_t)(~a);
            }
        }
    }
    __syncthreads();

    // --- phase C: register bitonic sort (descending) ---
    const int e1 = t, e2 = t + 1024;
    unsigned long long v1 = sk[e1];
    unsigned long long v2 = sk[e2];
    __syncthreads();
    for (int k = 2; k <= CAP; k <<= 1) {
        for (int j = k >> 1; j > 0; j >>= 1) {
            if (j >= 1024) {
                unsigned long long lo = v1 < v2 ? v1 : v2;
                unsigned long long hi = v1 < v2 ? v2 : v1;
                v1 = hi; v2 = lo;
            } else if (j >= 64) {
                sk[e1] = v1; sk[e2] = v2;
                __syncthreads();
                unsigned long long p1 = sk[e1 ^ j], p2 = sk[e2 ^ j];
                __syncthreads();
                {
                    bool takeMax = (((e1 & j) == 0) == ((e1 & k) == 0));
                    bool g = p1 > v1;
                    v1 = (takeMax == g) ? p1 : v1;
                }
                {
                    bool takeMax = (((e2 & j) == 0) == ((e2 & k) == 0));
                    bool g = p2 > v2;
                    v2 = (takeMax == g) ? p2 : v2;
                }
            } else {
                {
                    unsigned long long p1 =
                        (unsigned long long)__shfl_xor((long long)v1, j);
                    bool takeMax = (((e1 & j) == 0) == ((e1 & k) == 0));
                    bool g = p1 > v1;
                    v1 = (takeMax == g) ? p1 : v1;
                }
                {
                    unsigned long long p2 =
                        (unsigned long long)__shfl_xor((long long)v2, j);
                    bool takeMax = (((e2 & j) == 0) == ((e2 & k) == 0));
                    bool g = p2 > v2;
                    v2 = (takeMax == g) ? p2 : v2;
                }
            }
        }
    }
    // thread t holds rank-t key (ranks 0..1023) in v1
    unsigned long long key = v1;
    uint32_t u = (uint32_t)(key >> 32);
    int a = (u == 0) ? 0 : (int)(~(uint32_t)key);  // pad-safe index
    uint32_t fb = (u & 0x80000000u) ? (u ^ 0x80000000u) : ~u;
    float s = __uint_as_float(fb);  // masked score (NaN for pad)
    float4 bx = boxes[b * NA + a];  // precomputed xyxy (L2-resident)
    float c = (float)clsid[b * NA + a];
    float off = c * 7680.0f;
    obox[b * NK + t] =
        make_float4(bx.x + off, bx.y + off, bx.z + off, bx.w + off);
    float* dr = det + (size_t)(b * NK + t) * 8;
    dr[0] = bx.x; dr[1] = bx.y; dr[2] = bx.z; dr[3] = bx.w;
    dr[4] = s; dr[5] = c;
    bool keep0 = s > 0.25f;  // false for pad (NaN)
    unsigned long long bal = __ballot(keep0);
    if ((t & 63) == 0) keep0w[b * 16 + (t >> 6)] = bal;
}

// ---------------- K3: suppressed-by bitmask (j < i), transposed ----------
// Exact class prefilter: different classes have |x1_i - x1_j| >= 7678
// (offset 7680 apart, coords span < 2) -> IoU exactly 0 -> bit 0. Same
// class -> |dx| < 2 -> always passes. NaN pads fail -> bit 0 (as before).
__global__ void mask_kernel(const float4* __restrict__ obox,
                            unsigned long long* __restrict__ maskm) {
    int cb = blockIdx.x, rb = blockIdx.y, b = blockIdx.z;
    if (cb > rb) return;  // all j > i: implicitly zero, not stored
    int t = threadIdx.x;  // 64
    int i = rb * 64 + t;
    __shared__ float4 cbox[64];
    __shared__ float carea[64];
    int j0 = cb * 64;
    float4 c4 = obox[b * NK + j0 + t];
    cbox[t] = c4;
    carea[t] = (c4.z - c4.x) * (c4.w - c4.y);
    __syncthreads();
    float4 r4 = obox[b * NK + i];
    float ra = (r4.z - r4.x) * (r4.w - r4.y);
    unsigned long long word = 0;
    for (int jj = 0; jj < 64; ++jj) {
        int j = j0 + jj;
        float4 o = cbox[jj];
        if (j < i && fabsf(r4.x - o.x) < 3840.0f) {
            float ix1 = fmaxf(r4.x, o.x), iy1 = fmaxf(r4.y, o.y);
            float ix2 = fminf(r4.z, o.z), iy2 = fminf(r4.w, o.w);
            float iw = fmaxf(ix2 - ix1, 0.0f), ih = fmaxf(iy2 - iy1, 0.0f);
            float inter = iw * ih;
            float uni = ra + carea[jj] - inter;
            float iou = inter / (uni + 1e-9f);
            if (iou > 0.45f) word |= (1ULL << jj);
        }
    }
    maskm[(size_t)(b * 16 + cb) * NK + i] = word;
}

// ---------------- K4: Jacobi fixed-point NMS + output ----------------
__global__ void __launch_bounds__(1024)
jacobi_out_kernel(const unsigned long long* __restrict__ maskm,
                  const unsigned long long* __restrict__ keep0w,
                  const float* __restrict__ det,
                  float* __restrict__ out) {
    int b = blockIdx.x;
    int t = threadIdx.x;  // 1024; thread t owns row t
    int wid = t >> 6, lane = t & 63;
    __shared__ unsigned long long aliveS[16];
    __shared__ int changedS;
    __shared__ int list[ND];
    __shared__ int totalS;

    // triangular row load: words w > wid are identically zero
    unsigned long long row[16];
#pragma unroll
    for (int w = 0; w < 16; ++w)
        row[w] = (w <= wid) ? maskm[(size_t)(b * 16 + w) * NK + t] : 0ULL;
    bool keep0 = (keep0w[b * 16 + wid] >> lane) & 1ULL;
    if (t < 16) aliveS[t] = keep0w[b * 16 + t];
    __syncthreads();

    for (int it = 0; it < NK; ++it) {
        if (t == 0) changedS = 0;
        unsigned long long aw[16];
#pragma unroll
        for (int w = 0; w < 16; ++w) aw[w] = aliveS[w];  // snapshot (broadcast)
        __syncthreads();
        unsigned long long sup = 0;
#pragma unroll
        for (int w = 0; w < 16; ++w) sup |= aw[w] & row[w];
        bool newalive = keep0 && (sup == 0);
        unsigned long long bal = __ballot(newalive);
        if (lane == 0) {
            if (bal != aw[wid]) { atomicOr(&changedS, 1); aliveS[wid] = bal; }
        }
        __syncthreads();
        if (!changedS) break;
    }

    if (t < 64) {
        unsigned long long av = (lane < 16) ? aliveS[lane] : 0ULL;
        int cnt = (lane < 16) ? __popcll(av) : 0;
        int pre = cnt;
        for (int off = 1; off < 64; off <<= 1) {
            int v = __shfl_up(pre, off);
            if (lane >= off) pre += v;
        }
        int total = __shfl(pre, 63);
        int base = pre - cnt;
        if (lane == 0) totalS = total;
        if (lane < 16) {
            unsigned long long m = av;
            int pos = base;
            while (m && pos < ND) {
                int bit = __ffsll((long long)m) - 1;
                list[pos++] = lane * 64 + bit;
                m &= m - 1;
            }
        }
    }
    __syncthreads();
    if (t < ND) {
        float vals[6] = {0, 0, 0, 0, 0, 0};
        if (t < totalS) {
            const float* dr = det + (size_t)(b * NK + list[t]) * 8;
#pragma unroll
            for (int c = 0; c < 6; ++c) vals[c] = dr[c];
        }
        float* o = out + (size_t)(b * ND + t) * 6;
#pragma unroll
        for (int c = 0; c < 6; ++c) o[c] = vals[c];
    }
}

extern "C" void kernel_launch(void* const* d_in, const int* in_sizes, int n_in,
                              void* d_out, int out_size, void* d_ws, size_t ws_size,
                              hipStream_t stream) {
    const float* x = (const float*)d_in[0];
    float* out = (float*)d_out;

    char* ws = (char*)d_ws;
    size_t off = 0;
    auto alloc = [&](size_t bytes) {
        void* p = ws + off;
        off += (bytes + 255) & ~(size_t)255;
        return p;
    };
    float* scores = (float*)alloc((size_t)NB * NA * sizeof(float));
    int* clsid = (int*)alloc((size_t)NB * NA * sizeof(int));
    float4* boxes = (float4*)alloc((size_t)NB * NA * sizeof(float4));
    float4* obox = (float4*)alloc((size_t)NB * NK * sizeof(float4));
    float* det = (float*)alloc((size_t)NB * NK * 8 * sizeof(float));
    unsigned long long* keep0w =
        (unsigned long long*)alloc((size_t)NB * 16 * sizeof(unsigned long long));
    unsigned long long* maskm =
        (unsigned long long*)alloc((size_t)NB * NK * 16 * sizeof(unsigned long long));
    (void)ws_size;

    score_kernel<<<dim3(NA / 16, NB), 256, 0, stream>>>(x, scores, clsid,
                                                        boxes);
    select_sort_kernel<<<NB, 1024, 0, stream>>>(scores, boxes, clsid, obox,
                                                det, keep0w);
    mask_kernel<<<dim3(16, 16, NB), 64, 0, stream>>>(obox, maskm);
    jacobi_out_kernel<<<NB, 1024, 0, stream>>>(maskm, keep0w, det, out);
}